// Round 9
// baseline (1239.941 us; speedup 1.0000x reference)
//
#include <hip/hip_runtime.h>
#include <math.h>

#define NN 100000
#define NE 1600000
#define IN_DIM 512
#define HID 128
#define N_LAYERS 8
#define NB 98               // ceil(NN/1024)
#define PADMAX 3200000      // NE + 15*NN + slack
#define NBUCK 391           // ceil(NN/256)
#define RREP 4              // replica segments per bucket (atomic contention /4)
#define BCAP 1536           // capacity per segment: mean 1024 + 16 sigma

typedef __attribute__((ext_vector_type(4))) float f32x4;
typedef __attribute__((ext_vector_type(8))) _Float16 h16x8;
typedef __attribute__((ext_vector_type(2))) _Float16 h16x2;

// ---------------- CSR build (rows padded to multiples of 16, col-only) ----------------

__global__ void deg_count_kernel(const int* __restrict__ dst, int* __restrict__ deg) {
    int e = blockIdx.x * blockDim.x + threadIdx.x;
    if (e < NE) atomicAdd(&deg[dst[e]], 1);
}

__global__ void dinv_kernel(const int* __restrict__ deg, float* __restrict__ dinv) {
    int i = blockIdx.x * blockDim.x + threadIdx.x;
    if (i < NN) dinv[i] = rsqrtf((float)(deg[i] + 1));   // +1 self loop
}

__global__ void scan1_kernel(const int* __restrict__ deg, int* __restrict__ bsum) {
    __shared__ int s[16];
    int gi = blockIdx.x * 1024 + threadIdx.x;
    int d = (gi < NN) ? deg[gi] : 0;
    int r = (d + 15) & ~15;                              // padded capacity
    for (int off = 32; off; off >>= 1) r += __shfl_down(r, off, 64);
    if ((threadIdx.x & 63) == 0) s[threadIdx.x >> 6] = r;
    __syncthreads();
    if (threadIdx.x == 0) {
        int t = 0;
        for (int i = 0; i < 16; ++i) t += s[i];
        bsum[blockIdx.x] = t;
    }
}

__global__ void scan2_kernel(const int* __restrict__ bsum, int* __restrict__ boff,
                             int* __restrict__ row_ptr) {
    __shared__ int s[128];
    int tid = threadIdx.x;
    int v = (tid < NB) ? bsum[tid] : 0;
    s[tid] = v;
    __syncthreads();
    for (int off = 1; off < 128; off <<= 1) {
        int t = (tid >= off) ? s[tid - off] : 0;
        __syncthreads();
        s[tid] += t;
        __syncthreads();
    }
    if (tid < NB) boff[tid] = s[tid] - v;   // exclusive
    if (tid == NB - 1) row_ptr[NN] = s[tid];
}

__global__ void scan3_kernel(const int* __restrict__ deg, const int* __restrict__ boff,
                             int* __restrict__ row_ptr, int* __restrict__ cursor) {
    __shared__ int s[1024];
    int tid = threadIdx.x;
    int gi = blockIdx.x * 1024 + tid;
    int d = (gi < NN) ? deg[gi] : 0;
    int v = (d + 15) & ~15;
    s[tid] = v;
    __syncthreads();
    for (int off = 1; off < 1024; off <<= 1) {
        int t = (tid >= off) ? s[tid - off] : 0;
        __syncthreads();
        s[tid] += t;
        __syncthreads();
    }
    if (gi < NN) {
        int o = boff[blockIdx.x] + s[tid] - v;
        row_ptr[gi] = o;
        cursor[gi]  = o;
    }
}

__global__ void pad_kernel(const int* __restrict__ deg, const int* __restrict__ row_ptr,
                           int* __restrict__ col) {
    int i = blockIdx.x * 256 + threadIdx.x;
    if (i < NN) {
        int d = deg[i];
        int s = row_ptr[i] + d;
        int e = row_ptr[i] + ((d + 15) & ~15);
        for (int p = s; p < e; ++p) col[p] = NN;       // sentinel: y[NN] == 0
    }
}

// pass 1: scatter edges into coarse dst-buckets (sequential appends per segment)
__global__ void bucket_kernel(const int* __restrict__ src, const int* __restrict__ dst,
                              int* __restrict__ bcnt, int2* __restrict__ pairs) {
    int e = blockIdx.x * 256 + threadIdx.x;
    if (e < NE) {
        int s = src[e], d = dst[e];
        int cell = (d >> 8) * RREP + (blockIdx.x & (RREP - 1));
        int slot = atomicAdd(&bcnt[cell], 1);
        pairs[(size_t)cell * BCAP + slot] = make_int2(s, d);
    }
}

// pass 2: one block per bucket -> col writes localized to one ~65KB region
__global__ __launch_bounds__(256) void fill2_kernel(
    const int* __restrict__ bcnt, const int2* __restrict__ pairs,
    int* __restrict__ cursor, int* __restrict__ col) {
    int b = blockIdx.x;
#pragma unroll
    for (int r = 0; r < RREP; ++r) {
        int cell = b * RREP + r;
        int n = bcnt[cell];
        const int2* seg = pairs + (size_t)cell * BCAP;
        for (int i = threadIdx.x; i < n; i += 256) {
            int2 sd = seg[i];
            int pos = atomicAdd(&cursor[sd.y], 1);
            col[pos] = sd.x;
        }
    }
}

__global__ void zero_sentinel_kernel(_Float16* __restrict__ a, _Float16* __restrict__ b) {
    int t = threadIdx.x;                                // 128 threads
    a[(size_t)NN * HID + t] = (_Float16)0.f;
    b[(size_t)NN * HID + t] = (_Float16)0.f;
}

// ---------------- W prep: fp16 hi/lo split, MFMA B-fragment order ----------------
// B-frag element for (n,kk): B[k = kk*32 + (lane>>4)*8 + j][col = n*16 + (lane&15)]

__global__ void wprep_init_kernel(const float* __restrict__ W,
                                  _Float16* __restrict__ Bhi, _Float16* __restrict__ Blo) {
    int t = blockIdx.x * 256 + threadIdx.x;     // 8 * 16 * 64 = 8192 threads
    if (t >= 8 * 16 * 64) return;
    int lane = t & 63, nkk = t >> 6;
    int n = nkk >> 4, kk = nkk & 15;
    int scol = n * 16 + (lane & 15);
    int sr0 = kk * 32 + (lane >> 4) * 8;
#pragma unroll
    for (int j = 0; j < 8; ++j) {
        float w = W[(size_t)(sr0 + j) * HID + scol];
        _Float16 hi = (_Float16)w;
        _Float16 lo = (_Float16)(w - (float)hi);
        Bhi[(size_t)t * 8 + j] = hi;
        Blo[(size_t)t * 8 + j] = lo;
    }
}

__global__ void wprep_layers_kernel(const float* __restrict__ WL,
                                    _Float16* __restrict__ Bhi, _Float16* __restrict__ Blo) {
    int t = blockIdx.x * 256 + threadIdx.x;     // 8 layers * 8*4*64 = 16384 threads
    if (t >= N_LAYERS * 8 * 4 * 64) return;
    int layer = t >> 11;
    int r = t & 2047;
    int lane = r & 63, nkk = r >> 6;
    int n = nkk >> 2, kk = nkk & 3;
    const float* W = WL + (size_t)layer * HID * HID;
    int scol = n * 16 + (lane & 15);
    int sr0 = kk * 32 + (lane >> 4) * 8;
#pragma unroll
    for (int j = 0; j < 8; ++j) {
        float w = W[(size_t)(sr0 + j) * HID + scol];
        _Float16 hi = (_Float16)w;
        _Float16 lo = (_Float16)(w - (float)hi);
        Bhi[(size_t)t * 8 + j] = hi;
        Blo[(size_t)t * 8 + j] = lo;
    }
}

// ---------------- init projection -> y = fp16(dinv*h0), x0 = fp16(h0) ----------------
// 64 rows/block, 512 thr. Linear 128KB staging span, XOR-swizzled LDS tile.

__device__ inline int xsw(int row, int blk) {      // fp16 offset in [64][512] tile
    return row * 512 + ((blk ^ (row & 7)) << 3);
}

__global__ __launch_bounds__(512) void init_mfma_kernel(
    const float* __restrict__ x, const h16x8* __restrict__ Bhi, const h16x8* __restrict__ Blo,
    const float* __restrict__ b, const float* __restrict__ dinv,
    _Float16* __restrict__ ycur, _Float16* __restrict__ x0h) {
    __shared__ _Float16 xs[64 * 512];           // 64KB, swizzled blocks of 8 fp16
    int t = threadIdx.x;
    int row0 = blockIdx.x * 64;

#pragma unroll
    for (int i = 0; i < 8; ++i) {               // linear 32B chunks: c = t + 512*i
        int c = t + 512 * i;
        int row = c >> 6, blk = c & 63;
        int grow = row0 + row; if (grow >= NN) grow = NN - 1;
        const float* p = x + (size_t)grow * IN_DIM + blk * 8;
        float4 v0 = *(const float4*)p;
        float4 v1 = *(const float4*)(p + 4);
        h16x8 h;
        h[0] = (_Float16)v0.x; h[1] = (_Float16)v0.y;
        h[2] = (_Float16)v0.z; h[3] = (_Float16)v0.w;
        h[4] = (_Float16)v1.x; h[5] = (_Float16)v1.y;
        h[6] = (_Float16)v1.z; h[7] = (_Float16)v1.w;
        *(h16x8*)&xs[xsw(row, blk)] = h;
    }
    __syncthreads();

    int lane = t & 63, wid = t >> 6;            // wave = n-tile
    int rsel = lane & 15, ksel = lane >> 4;

    f32x4 acc[4];
#pragma unroll
    for (int m = 0; m < 4; ++m) acc[m] = (f32x4){0.f, 0.f, 0.f, 0.f};

#pragma unroll
    for (int kk = 0; kk < 16; ++kk) {
        h16x8 bh = Bhi[(wid * 16 + kk) * 64 + lane];
        h16x8 bl = Blo[(wid * 16 + kk) * 64 + lane];
#pragma unroll
        for (int m = 0; m < 4; ++m) {
            h16x8 a = *(const h16x8*)&xs[xsw(m * 16 + rsel, kk * 4 + ksel)];
            acc[m] = __builtin_amdgcn_mfma_f32_16x16x32_f16(a, bh, acc[m], 0, 0, 0);
            acc[m] = __builtin_amdgcn_mfma_f32_16x16x32_f16(a, bl, acc[m], 0, 0, 0);
        }
    }

    int col = wid * 16 + rsel;
    float bias = b[col];
#pragma unroll
    for (int m = 0; m < 4; ++m) {
#pragma unroll
        for (int r = 0; r < 4; ++r) {
            int row = row0 + m * 16 + ksel * 4 + r;
            if (row < NN) {
                float v = acc[m][r] + bias;
                float di = dinv[row];
                ycur[(size_t)row * HID + col] = (_Float16)(di * v);
                x0h[(size_t)row * HID + col]  = (_Float16)v;
            }
        }
    }
}

// ---------------- fused layer: agg(y) -> LDS -> MFMA -> relu/residual -> y_out ----------------
// agg_d = dinv_d * (sum_s y_s + y_d);  h = 0.9*agg + 0.1*x0
// out:  y_out = fp16(dinv_row * relu((1-b)h + b*(h@W)))

__device__ inline int hsw(int row, int blk) {      // fp16 offset in [64][128] tile
    return row * 128 + ((blk ^ (row & 7)) << 3);
}

__global__ __launch_bounds__(512) void fused_layer_kernel(
    const _Float16* __restrict__ y, const _Float16* __restrict__ x0,
    const int* __restrict__ row_ptr, const int* __restrict__ col,
    const float* __restrict__ dinv,
    const h16x8* __restrict__ Bhi, const h16x8* __restrict__ Blo,
    float beta, _Float16* __restrict__ yout) {
    __shared__ _Float16 hs[64 * 128];
    int t = threadIdx.x;
    int lane = t & 63, wid = t >> 6;
    int node0 = blockIdx.x * 64;

    // preload this wave's n-tile B fragments (independent of agg)
    h16x8 bh[4], bl[4];
#pragma unroll
    for (int kk = 0; kk < 4; ++kk) {
        bh[kk] = Bhi[(wid * 4 + kk) * 64 + lane];
        bl[kk] = Blo[(wid * 4 + kk) * 64 + lane];
    }

    // ---- agg phase: wave handles 8 nodes ----
    int g = lane >> 4, q = lane & 15;
    const h16x8* x8 = (const h16x8*)y;
    for (int i = 0; i < 8; ++i) {
        int lrow = wid * 8 + i;
        int node = node0 + lrow;
        if (node < NN) {
            float di = dinv[node];
            h16x8 sv = x8[(size_t)node * 16 + q];
            h16x8 zv = ((const h16x8*)x0)[(size_t)node * 16 + q];
            float acc[8];
#pragma unroll
            for (int j = 0; j < 8; ++j) acc[j] = 0.f;
            int p1 = row_ptr[node + 1];
            for (int p = row_ptr[node]; p < p1; p += 16) {
                int4 c4 = *(const int4*)(col + p + 4 * g);
                h16x8 v0 = x8[(size_t)c4.x * 16 + q];
                h16x8 v1 = x8[(size_t)c4.y * 16 + q];
                h16x8 v2 = x8[(size_t)c4.z * 16 + q];
                h16x8 v3 = x8[(size_t)c4.w * 16 + q];
#pragma unroll
                for (int j = 0; j < 8; ++j)
                    acc[j] += (float)v0[j] + (float)v1[j] + (float)v2[j] + (float)v3[j];
            }
#pragma unroll
            for (int j = 0; j < 8; ++j) {
                acc[j] += __shfl_xor(acc[j], 16, 64);
                acc[j] += __shfl_xor(acc[j], 32, 64);
            }
            if (g == 0) {
                h16x8 o16;
#pragma unroll
                for (int j = 0; j < 8; ++j) {
                    float s = acc[j] + (float)sv[j];       // + self y_d
                    o16[j] = (_Float16)(0.9f * (di * s) + 0.1f * (float)zv[j]);
                }
                *(h16x8*)&hs[hsw(lrow, q)] = o16;
            }
        } else if (g == 0) {
            h16x8 z;
#pragma unroll
            for (int j = 0; j < 8; ++j) z[j] = (_Float16)0.f;
            *(h16x8*)&hs[hsw(lrow, q)] = z;
        }
    }
    __syncthreads();

    // ---- MFMA phase: wave = n-tile wid, 4 m-tiles ----
    int rsel = lane & 15, ksel = lane >> 4;
    f32x4 acc[4];
#pragma unroll
    for (int m = 0; m < 4; ++m) acc[m] = (f32x4){0.f, 0.f, 0.f, 0.f};

#pragma unroll
    for (int m = 0; m < 4; ++m)
#pragma unroll
        for (int kk = 0; kk < 4; ++kk) {
            h16x8 a = *(const h16x8*)&hs[hsw(m * 16 + rsel, kk * 4 + ksel)];
            acc[m] = __builtin_amdgcn_mfma_f32_16x16x32_f16(a, bh[kk], acc[m], 0, 0, 0);
            acc[m] = __builtin_amdgcn_mfma_f32_16x16x32_f16(a, bl[kk], acc[m], 0, 0, 0);
        }

    float ob = 1.0f - beta;
    int colw = wid * 16 + rsel;
#pragma unroll
    for (int m = 0; m < 4; ++m) {
#pragma unroll
        for (int r = 0; r < 4; ++r) {
            int lr = m * 16 + ksel * 4 + r;
            int row = node0 + lr;
            if (row < NN) {
                float h = (float)hs[lr * 128 + (((colw >> 3) ^ (lr & 7)) << 3) + (colw & 7)];
                float v = ob * h + beta * acc[m][r];
                v = v > 0.f ? v : 0.f;
                yout[(size_t)row * HID + colw] = (_Float16)(dinv[row] * v);
            }
        }
    }
}

// ---------------- final projection: out = sqrt(deg+1) * (y . w) + b ----------------

__global__ __launch_bounds__(256) void final16_kernel(
    const _Float16* __restrict__ y, const int* __restrict__ deg,
    const float* __restrict__ Wout, const float* __restrict__ bout,
    float* __restrict__ out) {
    int node = blockIdx.x * 4 + (threadIdx.x >> 6);
    int lane = threadIdx.x & 63;
    h16x2 a = ((const h16x2*)y)[(size_t)node * 64 + lane];
    float2 w = ((const float2*)Wout)[lane];
    float v = (float)a[0] * w.x + (float)a[1] * w.y;
#pragma unroll
    for (int off = 32; off; off >>= 1) v += __shfl_down(v, off, 64);
    if (lane == 0) out[node] = v * sqrtf((float)(deg[node] + 1)) + bout[0];
}

// ---------------- host ----------------

extern "C" void kernel_launch(void* const* d_in, const int* in_sizes, int n_in,
                              void* d_out, int out_size, void* d_ws, size_t ws_size,
                              hipStream_t stream) {
    const float* x_in     = (const float*)d_in[0];
    const int*   ei       = (const int*)d_in[1];
    const float* W_in     = (const float*)d_in[3];
    const float* b_in     = (const float*)d_in[4];
    const float* W_layers = (const float*)d_in[5];
    const float* W_out    = (const float*)d_in[6];
    const float* b_out    = (const float*)d_in[7];
    float* out = (float*)d_out;

    const int* src = ei;
    const int* dst = ei + NE;

    char* ws = (char*)d_ws;
    size_t off = 0;
    auto alloc = [&](size_t bytes) {
        size_t p = off;
        off = (off + bytes + 255) & ~(size_t)255;
        return p;
    };
    int*   deg     = (int*)(ws + alloc((size_t)NN * 4));
    float* dinv    = (float*)(ws + alloc((size_t)NN * 4));
    int*   row_ptr = (int*)(ws + alloc((size_t)(NN + 1) * 4));
    int*   cursor  = (int*)(ws + alloc((size_t)NN * 4));
    int*   bsum    = (int*)(ws + alloc((size_t)NB * 4));
    int*   boff    = (int*)(ws + alloc((size_t)NB * 4));
    int*   bcnt    = (int*)(ws + alloc((size_t)NBUCK * RREP * 4));
    int*   col     = (int*)(ws + alloc((size_t)PADMAX * 4));
    size_t x0_off  = alloc((size_t)NN * HID * 2);
    _Float16* x0h  = (_Float16*)(ws + x0_off);
    int2*  pairs   = (int2*)(ws + x0_off);      // aliases x0h: CSR build finishes
                                                // before init_mfma writes x0h (same stream)
    _Float16* bufA = (_Float16*)(ws + alloc((size_t)(NN + 16) * HID * 2));
    _Float16* bufB = (_Float16*)(ws + alloc((size_t)(NN + 16) * HID * 2));
    _Float16* Bhi0 = (_Float16*)(ws + alloc((size_t)IN_DIM * HID * 2));
    _Float16* Blo0 = (_Float16*)(ws + alloc((size_t)IN_DIM * HID * 2));
    _Float16* BhiL = (_Float16*)(ws + alloc((size_t)N_LAYERS * HID * HID * 2));
    _Float16* BloL = (_Float16*)(ws + alloc((size_t)N_LAYERS * HID * HID * 2));

    hipMemsetAsync(deg, 0, (size_t)NN * 4, stream);
    hipMemsetAsync(bcnt, 0, (size_t)NBUCK * RREP * 4, stream);

    deg_count_kernel<<<NE / 256, 256, 0, stream>>>(dst, deg);
    dinv_kernel<<<(NN + 255) / 256, 256, 0, stream>>>(deg, dinv);
    scan1_kernel<<<NB, 1024, 0, stream>>>(deg, bsum);
    scan2_kernel<<<1, 128, 0, stream>>>(bsum, boff, row_ptr);
    scan3_kernel<<<NB, 1024, 0, stream>>>(deg, boff, row_ptr, cursor);
    pad_kernel<<<(NN + 255) / 256, 256, 0, stream>>>(deg, row_ptr, col);
    bucket_kernel<<<NE / 256, 256, 0, stream>>>(src, dst, bcnt, pairs);
    fill2_kernel<<<NBUCK, 256, 0, stream>>>(bcnt, pairs, cursor, col);
    zero_sentinel_kernel<<<1, 128, 0, stream>>>(bufA, bufB);

    wprep_init_kernel<<<32, 256, 0, stream>>>(W_in, Bhi0, Blo0);
    wprep_layers_kernel<<<64, 256, 0, stream>>>(W_layers, BhiL, BloL);

    init_mfma_kernel<<<(NN + 63) / 64, 512, 0, stream>>>(
        x_in, (const h16x8*)Bhi0, (const h16x8*)Blo0, b_in, dinv, bufA, x0h);

    _Float16* cur = bufA;
    _Float16* nxt = bufB;
    for (int l = 0; l < N_LAYERS; ++l) {
        float beta = logf(0.5f / (float)(l + 1) + 1.0f);
        fused_layer_kernel<<<(NN + 63) / 64, 512, 0, stream>>>(
            cur, x0h, row_ptr, col, dinv,
            (const h16x8*)(BhiL + (size_t)l * HID * HID),
            (const h16x8*)(BloL + (size_t)l * HID * HID), beta, nxt);
        _Float16* tmp = cur; cur = nxt; nxt = tmp;
    }

    final16_kernel<<<NN / 4, 256, 0, stream>>>(cur, deg, W_out, b_out, out);
}

// Round 10
// 1048.002 us; speedup vs baseline: 1.1831x; 1.1831x over previous
//
#include <hip/hip_runtime.h>
#include <math.h>

#define NN 100000
#define NE 1600000
#define IN_DIM 512
#define HID 128
#define N_LAYERS 8
#define NB 98               // ceil(NN/1024)
#define PADMAX 3200000      // NE + 15*NN + slack
#define NBUCK 391           // ceil(NN/256)
#define BCAP2 4608          // per-bucket capacity: mean 4096 + 8 sigma
#define EPB 4096            // edges per bucket2 block

typedef __attribute__((ext_vector_type(4))) float f32x4;
typedef __attribute__((ext_vector_type(8))) _Float16 h16x8;
typedef __attribute__((ext_vector_type(2))) _Float16 h16x2;

// ---------------- CSR build (rows padded to multiples of 16, col-only) ----------------

__global__ void deg_count_kernel(const int* __restrict__ dst, int* __restrict__ deg) {
    int e = blockIdx.x * blockDim.x + threadIdx.x;
    if (e < NE) atomicAdd(&deg[dst[e]], 1);
}

__global__ void dinv_kernel(const int* __restrict__ deg, float* __restrict__ dinv) {
    int i = blockIdx.x * blockDim.x + threadIdx.x;
    if (i < NN) dinv[i] = rsqrtf((float)(deg[i] + 1));   // +1 self loop
}

__global__ void scan1_kernel(const int* __restrict__ deg, int* __restrict__ bsum) {
    __shared__ int s[16];
    int gi = blockIdx.x * 1024 + threadIdx.x;
    int d = (gi < NN) ? deg[gi] : 0;
    int r = (d + 15) & ~15;                              // padded capacity
    for (int off = 32; off; off >>= 1) r += __shfl_down(r, off, 64);
    if ((threadIdx.x & 63) == 0) s[threadIdx.x >> 6] = r;
    __syncthreads();
    if (threadIdx.x == 0) {
        int t = 0;
        for (int i = 0; i < 16; ++i) t += s[i];
        bsum[blockIdx.x] = t;
    }
}

__global__ void scan2_kernel(const int* __restrict__ bsum, int* __restrict__ boff,
                             int* __restrict__ row_ptr) {
    __shared__ int s[128];
    int tid = threadIdx.x;
    int v = (tid < NB) ? bsum[tid] : 0;
    s[tid] = v;
    __syncthreads();
    for (int off = 1; off < 128; off <<= 1) {
        int t = (tid >= off) ? s[tid - off] : 0;
        __syncthreads();
        s[tid] += t;
        __syncthreads();
    }
    if (tid < NB) boff[tid] = s[tid] - v;   // exclusive
    if (tid == NB - 1) row_ptr[NN] = s[tid];
}

__global__ void scan3_kernel(const int* __restrict__ deg, const int* __restrict__ boff,
                             int* __restrict__ row_ptr, int* __restrict__ cursor) {
    __shared__ int s[1024];
    int tid = threadIdx.x;
    int gi = blockIdx.x * 1024 + tid;
    int d = (gi < NN) ? deg[gi] : 0;
    int v = (d + 15) & ~15;
    s[tid] = v;
    __syncthreads();
    for (int off = 1; off < 1024; off <<= 1) {
        int t = (tid >= off) ? s[tid - off] : 0;
        __syncthreads();
        s[tid] += t;
        __syncthreads();
    }
    if (gi < NN) {
        int o = boff[blockIdx.x] + s[tid] - v;
        row_ptr[gi] = o;
        cursor[gi]  = o;
    }
}

__global__ void pad_kernel(const int* __restrict__ deg, const int* __restrict__ row_ptr,
                           int* __restrict__ col) {
    int i = blockIdx.x * 256 + threadIdx.x;
    if (i < NN) {
        int d = deg[i];
        int s = row_ptr[i] + d;
        int e = row_ptr[i] + ((d + 15) & ~15);
        for (int p = s; p < e; ++p) col[p] = NN;       // sentinel: y[NN] == 0
    }
}

// pass 1: block-local counting sort of 4096 edges by dst-bucket (dst>>8).
// LDS histogram -> scan -> one global atomic per (block,bucket) to reserve
// space -> stable LDS binning -> coalesced contiguous chunk write-out.
__global__ __launch_bounds__(256) void bucket2_kernel(
    const int* __restrict__ src, const int* __restrict__ dst,
    int* __restrict__ bcnt, int2* __restrict__ pairs) {
    __shared__ int hist[NBUCK];
    __shared__ int scan_[NBUCK + 1];
    __shared__ int gb[NBUCK];
    __shared__ int curs[NBUCK];
    __shared__ int2 lp[EPB];                 // 32KB
    int t = threadIdx.x;
    int e0 = blockIdx.x * EPB;
    int ne = NE - e0; if (ne > EPB) ne = EPB;

    for (int i = t; i < NBUCK; i += 256) hist[i] = 0;
    __syncthreads();
    for (int i = t; i < ne; i += 256)
        atomicAdd(&hist[dst[e0 + i] >> 8], 1);
    __syncthreads();

    // exclusive scan over 391 buckets (wave 0, 7 chunks of 64)
    if (t < 64) {
        int run = 0;
        for (int c = 0; c < 7; ++c) {
            int i = c * 64 + t;
            int h = (i < NBUCK) ? hist[i] : 0;
            int v = h;
            for (int off = 1; off < 64; off <<= 1) {
                int tmp = __shfl_up(v, off, 64);
                if (t >= off) v += tmp;
            }
            if (i < NBUCK) scan_[i] = run + v - h;
            run += __shfl(v, 63, 64);
        }
        if (t == 0) scan_[NBUCK] = run;      // == ne
    }
    __syncthreads();

    // reserve global space per bucket; init LDS cursors
    for (int i = t; i < NBUCK; i += 256) {
        int h = hist[i];
        gb[i] = h ? atomicAdd(&bcnt[i], h) : 0;
        curs[i] = scan_[i];
    }
    __syncthreads();

    // stable binning into LDS
    for (int i = t; i < ne; i += 256) {
        int d = dst[e0 + i], s = src[e0 + i];
        int slot = atomicAdd(&curs[d >> 8], 1);
        lp[slot] = make_int2(s, d);
    }
    __syncthreads();

    // coalesced write-out: LDS slot i -> bucket b (binary search), contiguous chunk
    for (int i = t; i < ne; i += 256) {
        int lo = 0, hi = NBUCK;              // scan_[lo] <= i < scan_[hi]
        while (hi - lo > 1) {
            int mid = (lo + hi) >> 1;
            if (scan_[mid] <= i) lo = mid; else hi = mid;
        }
        pairs[(size_t)lo * BCAP2 + gb[lo] + (i - scan_[lo])] = lp[i];
    }
}

// pass 2: one block per bucket -> col writes localized to one ~65KB region (one XCD)
__global__ __launch_bounds__(512) void fill2_kernel(
    const int* __restrict__ bcnt, const int2* __restrict__ pairs,
    int* __restrict__ cursor, int* __restrict__ col) {
    int b = blockIdx.x;
    int n = bcnt[b];
    const int2* seg = pairs + (size_t)b * BCAP2;
#pragma unroll 4
    for (int i = threadIdx.x; i < n; i += 512) {
        int2 sd = seg[i];
        int pos = atomicAdd(&cursor[sd.y], 1);
        col[pos] = sd.x;
    }
}

__global__ void zero_sentinel_kernel(_Float16* __restrict__ a, _Float16* __restrict__ b) {
    int t = threadIdx.x;                                // 128 threads
    a[(size_t)NN * HID + t] = (_Float16)0.f;
    b[(size_t)NN * HID + t] = (_Float16)0.f;
}

// ---------------- W prep: fp16 hi/lo split, MFMA B-fragment order ----------------
// B-frag element for (n,kk): B[k = kk*32 + (lane>>4)*8 + j][col = n*16 + (lane&15)]

__global__ void wprep_init_kernel(const float* __restrict__ W,
                                  _Float16* __restrict__ Bhi, _Float16* __restrict__ Blo) {
    int t = blockIdx.x * 256 + threadIdx.x;     // 8 * 16 * 64 = 8192 threads
    if (t >= 8 * 16 * 64) return;
    int lane = t & 63, nkk = t >> 6;
    int n = nkk >> 4, kk = nkk & 15;
    int scol = n * 16 + (lane & 15);
    int sr0 = kk * 32 + (lane >> 4) * 8;
#pragma unroll
    for (int j = 0; j < 8; ++j) {
        float w = W[(size_t)(sr0 + j) * HID + scol];
        _Float16 hi = (_Float16)w;
        _Float16 lo = (_Float16)(w - (float)hi);
        Bhi[(size_t)t * 8 + j] = hi;
        Blo[(size_t)t * 8 + j] = lo;
    }
}

__global__ void wprep_layers_kernel(const float* __restrict__ WL,
                                    _Float16* __restrict__ Bhi, _Float16* __restrict__ Blo) {
    int t = blockIdx.x * 256 + threadIdx.x;     // 8 layers * 8*4*64 = 16384 threads
    if (t >= N_LAYERS * 8 * 4 * 64) return;
    int layer = t >> 11;
    int r = t & 2047;
    int lane = r & 63, nkk = r >> 6;
    int n = nkk >> 2, kk = nkk & 3;
    const float* W = WL + (size_t)layer * HID * HID;
    int scol = n * 16 + (lane & 15);
    int sr0 = kk * 32 + (lane >> 4) * 8;
#pragma unroll
    for (int j = 0; j < 8; ++j) {
        float w = W[(size_t)(sr0 + j) * HID + scol];
        _Float16 hi = (_Float16)w;
        _Float16 lo = (_Float16)(w - (float)hi);
        Bhi[(size_t)t * 8 + j] = hi;
        Blo[(size_t)t * 8 + j] = lo;
    }
}

// ---------------- init projection -> y = fp16(dinv*h0), x0 = fp16(h0) ----------------
// 64 rows/block, 512 thr. Linear 128KB staging span, XOR-swizzled LDS tile.

__device__ inline int xsw(int row, int blk) {      // fp16 offset in [64][512] tile
    return row * 512 + ((blk ^ (row & 7)) << 3);
}

__global__ __launch_bounds__(512) void init_mfma_kernel(
    const float* __restrict__ x, const h16x8* __restrict__ Bhi, const h16x8* __restrict__ Blo,
    const float* __restrict__ b, const float* __restrict__ dinv,
    _Float16* __restrict__ ycur, _Float16* __restrict__ x0h) {
    __shared__ _Float16 xs[64 * 512];           // 64KB, swizzled blocks of 8 fp16
    int t = threadIdx.x;
    int row0 = blockIdx.x * 64;

#pragma unroll
    for (int i = 0; i < 8; ++i) {               // linear 32B chunks: c = t + 512*i
        int c = t + 512 * i;
        int row = c >> 6, blk = c & 63;
        int grow = row0 + row; if (grow >= NN) grow = NN - 1;
        const float* p = x + (size_t)grow * IN_DIM + blk * 8;
        float4 v0 = *(const float4*)p;
        float4 v1 = *(const float4*)(p + 4);
        h16x8 h;
        h[0] = (_Float16)v0.x; h[1] = (_Float16)v0.y;
        h[2] = (_Float16)v0.z; h[3] = (_Float16)v0.w;
        h[4] = (_Float16)v1.x; h[5] = (_Float16)v1.y;
        h[6] = (_Float16)v1.z; h[7] = (_Float16)v1.w;
        *(h16x8*)&xs[xsw(row, blk)] = h;
    }
    __syncthreads();

    int lane = t & 63, wid = t >> 6;            // wave = n-tile
    int rsel = lane & 15, ksel = lane >> 4;

    f32x4 acc[4];
#pragma unroll
    for (int m = 0; m < 4; ++m) acc[m] = (f32x4){0.f, 0.f, 0.f, 0.f};

#pragma unroll
    for (int kk = 0; kk < 16; ++kk) {
        h16x8 bh = Bhi[(wid * 16 + kk) * 64 + lane];
        h16x8 bl = Blo[(wid * 16 + kk) * 64 + lane];
#pragma unroll
        for (int m = 0; m < 4; ++m) {
            h16x8 a = *(const h16x8*)&xs[xsw(m * 16 + rsel, kk * 4 + ksel)];
            acc[m] = __builtin_amdgcn_mfma_f32_16x16x32_f16(a, bh, acc[m], 0, 0, 0);
            acc[m] = __builtin_amdgcn_mfma_f32_16x16x32_f16(a, bl, acc[m], 0, 0, 0);
        }
    }

    int col = wid * 16 + rsel;
    float bias = b[col];
#pragma unroll
    for (int m = 0; m < 4; ++m) {
#pragma unroll
        for (int r = 0; r < 4; ++r) {
            int row = row0 + m * 16 + ksel * 4 + r;
            if (row < NN) {
                float v = acc[m][r] + bias;
                float di = dinv[row];
                ycur[(size_t)row * HID + col] = (_Float16)(di * v);
                x0h[(size_t)row * HID + col]  = (_Float16)v;
            }
        }
    }
}

// ---------------- fused layer: agg(y) -> LDS -> MFMA -> relu/residual -> y_out ----------------
// agg_d = dinv_d * (sum_s y_s + y_d);  h = 0.9*agg + 0.1*x0
// out:  y_out = fp16(dinv_row * relu((1-b)h + b*(h@W)))

__device__ inline int hsw(int row, int blk) {      // fp16 offset in [64][128] tile
    return row * 128 + ((blk ^ (row & 7)) << 3);
}

__global__ __launch_bounds__(512) void fused_layer_kernel(
    const _Float16* __restrict__ y, const _Float16* __restrict__ x0,
    const int* __restrict__ row_ptr, const int* __restrict__ col,
    const float* __restrict__ dinv,
    const h16x8* __restrict__ Bhi, const h16x8* __restrict__ Blo,
    float beta, _Float16* __restrict__ yout) {
    __shared__ _Float16 hs[64 * 128];
    int t = threadIdx.x;
    int lane = t & 63, wid = t >> 6;
    int node0 = blockIdx.x * 64;

    // preload this wave's n-tile B fragments (independent of agg)
    h16x8 bh[4], bl[4];
#pragma unroll
    for (int kk = 0; kk < 4; ++kk) {
        bh[kk] = Bhi[(wid * 4 + kk) * 64 + lane];
        bl[kk] = Blo[(wid * 4 + kk) * 64 + lane];
    }

    // ---- agg phase: wave handles 8 nodes ----
    int g = lane >> 4, q = lane & 15;
    const h16x8* x8 = (const h16x8*)y;
    for (int i = 0; i < 8; ++i) {
        int lrow = wid * 8 + i;
        int node = node0 + lrow;
        if (node < NN) {
            float di = dinv[node];
            h16x8 sv = x8[(size_t)node * 16 + q];
            h16x8 zv = ((const h16x8*)x0)[(size_t)node * 16 + q];
            float acc[8];
#pragma unroll
            for (int j = 0; j < 8; ++j) acc[j] = 0.f;
            int p1 = row_ptr[node + 1];
#pragma unroll 2
            for (int p = row_ptr[node]; p < p1; p += 16) {
                int4 c4 = *(const int4*)(col + p + 4 * g);
                h16x8 v0 = x8[(size_t)c4.x * 16 + q];
                h16x8 v1 = x8[(size_t)c4.y * 16 + q];
                h16x8 v2 = x8[(size_t)c4.z * 16 + q];
                h16x8 v3 = x8[(size_t)c4.w * 16 + q];
#pragma unroll
                for (int j = 0; j < 8; ++j)
                    acc[j] += (float)v0[j] + (float)v1[j] + (float)v2[j] + (float)v3[j];
            }
#pragma unroll
            for (int j = 0; j < 8; ++j) {
                acc[j] += __shfl_xor(acc[j], 16, 64);
                acc[j] += __shfl_xor(acc[j], 32, 64);
            }
            if (g == 0) {
                h16x8 o16;
#pragma unroll
                for (int j = 0; j < 8; ++j) {
                    float s = acc[j] + (float)sv[j];       // + self y_d
                    o16[j] = (_Float16)(0.9f * (di * s) + 0.1f * (float)zv[j]);
                }
                *(h16x8*)&hs[hsw(lrow, q)] = o16;
            }
        } else if (g == 0) {
            h16x8 z;
#pragma unroll
            for (int j = 0; j < 8; ++j) z[j] = (_Float16)0.f;
            *(h16x8*)&hs[hsw(lrow, q)] = z;
        }
    }
    __syncthreads();

    // ---- MFMA phase: wave = n-tile wid, 4 m-tiles ----
    int rsel = lane & 15, ksel = lane >> 4;
    f32x4 acc[4];
#pragma unroll
    for (int m = 0; m < 4; ++m) acc[m] = (f32x4){0.f, 0.f, 0.f, 0.f};

#pragma unroll
    for (int m = 0; m < 4; ++m)
#pragma unroll
        for (int kk = 0; kk < 4; ++kk) {
            h16x8 a = *(const h16x8*)&hs[hsw(m * 16 + rsel, kk * 4 + ksel)];
            acc[m] = __builtin_amdgcn_mfma_f32_16x16x32_f16(a, bh[kk], acc[m], 0, 0, 0);
            acc[m] = __builtin_amdgcn_mfma_f32_16x16x32_f16(a, bl[kk], acc[m], 0, 0, 0);
        }

    float ob = 1.0f - beta;
    int colw = wid * 16 + rsel;
#pragma unroll
    for (int m = 0; m < 4; ++m) {
#pragma unroll
        for (int r = 0; r < 4; ++r) {
            int lr = m * 16 + ksel * 4 + r;
            int row = node0 + lr;
            if (row < NN) {
                float h = (float)hs[lr * 128 + (((colw >> 3) ^ (lr & 7)) << 3) + (colw & 7)];
                float v = ob * h + beta * acc[m][r];
                v = v > 0.f ? v : 0.f;
                yout[(size_t)row * HID + colw] = (_Float16)(dinv[row] * v);
            }
        }
    }
}

// ---------------- final projection: out = sqrt(deg+1) * (y . w) + b ----------------

__global__ __launch_bounds__(256) void final16_kernel(
    const _Float16* __restrict__ y, const int* __restrict__ deg,
    const float* __restrict__ Wout, const float* __restrict__ bout,
    float* __restrict__ out) {
    int node = blockIdx.x * 4 + (threadIdx.x >> 6);
    int lane = threadIdx.x & 63;
    h16x2 a = ((const h16x2*)y)[(size_t)node * 64 + lane];
    float2 w = ((const float2*)Wout)[lane];
    float v = (float)a[0] * w.x + (float)a[1] * w.y;
#pragma unroll
    for (int off = 32; off; off >>= 1) v += __shfl_down(v, off, 64);
    if (lane == 0) out[node] = v * sqrtf((float)(deg[node] + 1)) + bout[0];
}

// ---------------- host ----------------

extern "C" void kernel_launch(void* const* d_in, const int* in_sizes, int n_in,
                              void* d_out, int out_size, void* d_ws, size_t ws_size,
                              hipStream_t stream) {
    const float* x_in     = (const float*)d_in[0];
    const int*   ei       = (const int*)d_in[1];
    const float* W_in     = (const float*)d_in[3];
    const float* b_in     = (const float*)d_in[4];
    const float* W_layers = (const float*)d_in[5];
    const float* W_out    = (const float*)d_in[6];
    const float* b_out    = (const float*)d_in[7];
    float* out = (float*)d_out;

    const int* src = ei;
    const int* dst = ei + NE;

    char* ws = (char*)d_ws;
    size_t off = 0;
    auto alloc = [&](size_t bytes) {
        size_t p = off;
        off = (off + bytes + 255) & ~(size_t)255;
        return p;
    };
    int*   deg     = (int*)(ws + alloc((size_t)NN * 4));
    float* dinv    = (float*)(ws + alloc((size_t)NN * 4));
    int*   row_ptr = (int*)(ws + alloc((size_t)(NN + 1) * 4));
    int*   cursor  = (int*)(ws + alloc((size_t)NN * 4));
    int*   bsum    = (int*)(ws + alloc((size_t)NB * 4));
    int*   boff    = (int*)(ws + alloc((size_t)NB * 4));
    int*   bcnt    = (int*)(ws + alloc((size_t)NBUCK * 4));
    int*   col     = (int*)(ws + alloc((size_t)PADMAX * 4));
    size_t x0_off  = alloc((size_t)NN * HID * 2);
    _Float16* x0h  = (_Float16*)(ws + x0_off);
    int2*  pairs   = (int2*)(ws + x0_off);      // aliases x0h (14.4MB < 25.6MB):
                                                // CSR build completes before init_mfma
                                                // writes x0h (same stream)
    _Float16* bufA = (_Float16*)(ws + alloc((size_t)(NN + 16) * HID * 2));
    _Float16* bufB = (_Float16*)(ws + alloc((size_t)(NN + 16) * HID * 2));
    _Float16* Bhi0 = (_Float16*)(ws + alloc((size_t)IN_DIM * HID * 2));
    _Float16* Blo0 = (_Float16*)(ws + alloc((size_t)IN_DIM * HID * 2));
    _Float16* BhiL = (_Float16*)(ws + alloc((size_t)N_LAYERS * HID * HID * 2));
    _Float16* BloL = (_Float16*)(ws + alloc((size_t)N_LAYERS * HID * HID * 2));

    hipMemsetAsync(deg, 0, (size_t)NN * 4, stream);
    hipMemsetAsync(bcnt, 0, (size_t)NBUCK * 4, stream);

    deg_count_kernel<<<NE / 256, 256, 0, stream>>>(dst, deg);
    dinv_kernel<<<(NN + 255) / 256, 256, 0, stream>>>(deg, dinv);
    scan1_kernel<<<NB, 1024, 0, stream>>>(deg, bsum);
    scan2_kernel<<<1, 128, 0, stream>>>(bsum, boff, row_ptr);
    scan3_kernel<<<NB, 1024, 0, stream>>>(deg, boff, row_ptr, cursor);
    pad_kernel<<<(NN + 255) / 256, 256, 0, stream>>>(deg, row_ptr, col);
    bucket2_kernel<<<(NE + EPB - 1) / EPB, 256, 0, stream>>>(src, dst, bcnt, pairs);
    fill2_kernel<<<NBUCK, 512, 0, stream>>>(bcnt, pairs, cursor, col);
    zero_sentinel_kernel<<<1, 128, 0, stream>>>(bufA, bufB);

    wprep_init_kernel<<<32, 256, 0, stream>>>(W_in, Bhi0, Blo0);
    wprep_layers_kernel<<<64, 256, 0, stream>>>(W_layers, BhiL, BloL);

    init_mfma_kernel<<<(NN + 63) / 64, 512, 0, stream>>>(
        x_in, (const h16x8*)Bhi0, (const h16x8*)Blo0, b_in, dinv, bufA, x0h);

    _Float16* cur = bufA;
    _Float16* nxt = bufB;
    for (int l = 0; l < N_LAYERS; ++l) {
        float beta = logf(0.5f / (float)(l + 1) + 1.0f);
        fused_layer_kernel<<<(NN + 63) / 64, 512, 0, stream>>>(
            cur, x0h, row_ptr, col, dinv,
            (const h16x8*)(BhiL + (size_t)l * HID * HID),
            (const h16x8*)(BloL + (size_t)l * HID * HID), beta, nxt);
        _Float16* tmp = cur; cur = nxt; nxt = tmp;
    }

    final16_kernel<<<NN / 4, 256, 0, stream>>>(cur, deg, W_out, b_out, out);
}

// Round 11
// 947.309 us; speedup vs baseline: 1.3089x; 1.1063x over previous
//
#include <hip/hip_runtime.h>
#include <math.h>

#define NN 100000
#define NE 1600000
#define IN_DIM 512
#define HID 128
#define N_LAYERS 8
#define NB 98               // ceil(NN/1024)
#define PADMAX 2000000      // NE + 3*NN + slack (rows padded to mult of 4)
#define NBUCK 391           // ceil(NN/256)
#define BCAP2 4608          // per-bucket capacity: mean 4096 + 8 sigma
#define EPB 4096            // edges per bucket2 block

typedef __attribute__((ext_vector_type(4))) float f32x4;
typedef __attribute__((ext_vector_type(8))) _Float16 h16x8;
typedef __attribute__((ext_vector_type(2))) _Float16 h16x2;

// ---------------- CSR build (rows padded to multiples of 4, col-only) ----------------

__global__ void deg_count_kernel(const int* __restrict__ dst, int* __restrict__ deg) {
    int e = blockIdx.x * blockDim.x + threadIdx.x;
    if (e < NE) atomicAdd(&deg[dst[e]], 1);
}

__global__ void dinv_kernel(const int* __restrict__ deg, float* __restrict__ dinv) {
    int i = blockIdx.x * blockDim.x + threadIdx.x;
    if (i < NN) dinv[i] = rsqrtf((float)(deg[i] + 1));   // +1 self loop
}

__global__ void scan1_kernel(const int* __restrict__ deg, int* __restrict__ bsum) {
    __shared__ int s[16];
    int gi = blockIdx.x * 1024 + threadIdx.x;
    int d = (gi < NN) ? deg[gi] : 0;
    int r = (d + 3) & ~3;                                // padded capacity
    for (int off = 32; off; off >>= 1) r += __shfl_down(r, off, 64);
    if ((threadIdx.x & 63) == 0) s[threadIdx.x >> 6] = r;
    __syncthreads();
    if (threadIdx.x == 0) {
        int t = 0;
        for (int i = 0; i < 16; ++i) t += s[i];
        bsum[blockIdx.x] = t;
    }
}

__global__ void scan2_kernel(const int* __restrict__ bsum, int* __restrict__ boff,
                             int* __restrict__ row_ptr) {
    __shared__ int s[128];
    int tid = threadIdx.x;
    int v = (tid < NB) ? bsum[tid] : 0;
    s[tid] = v;
    __syncthreads();
    for (int off = 1; off < 128; off <<= 1) {
        int t = (tid >= off) ? s[tid - off] : 0;
        __syncthreads();
        s[tid] += t;
        __syncthreads();
    }
    if (tid < NB) boff[tid] = s[tid] - v;   // exclusive
    if (tid == NB - 1) row_ptr[NN] = s[tid];
}

__global__ void scan3_kernel(const int* __restrict__ deg, const int* __restrict__ boff,
                             int* __restrict__ row_ptr, int* __restrict__ cursor) {
    __shared__ int s[1024];
    int tid = threadIdx.x;
    int gi = blockIdx.x * 1024 + tid;
    int d = (gi < NN) ? deg[gi] : 0;
    int v = (d + 3) & ~3;
    s[tid] = v;
    __syncthreads();
    for (int off = 1; off < 1024; off <<= 1) {
        int t = (tid >= off) ? s[tid - off] : 0;
        __syncthreads();
        s[tid] += t;
        __syncthreads();
    }
    if (gi < NN) {
        int o = boff[blockIdx.x] + s[tid] - v;
        row_ptr[gi] = o;
        cursor[gi]  = o;
    }
}

__global__ void pad_kernel(const int* __restrict__ deg, const int* __restrict__ row_ptr,
                           int* __restrict__ col) {
    int i = blockIdx.x * 256 + threadIdx.x;
    if (i < NN) {
        int d = deg[i];
        int s = row_ptr[i] + d;
        int e = row_ptr[i] + ((d + 3) & ~3);
        for (int p = s; p < e; ++p) col[p] = NN;       // sentinel: y[NN] == 0
    }
}

// pass 1: block-local counting sort of 4096 edges by dst-bucket (dst>>8).
__global__ __launch_bounds__(256) void bucket2_kernel(
    const int* __restrict__ src, const int* __restrict__ dst,
    int* __restrict__ bcnt, int2* __restrict__ pairs) {
    __shared__ int hist[NBUCK];
    __shared__ int scan_[NBUCK + 1];
    __shared__ int gb[NBUCK];
    __shared__ int curs[NBUCK];
    __shared__ int2 lp[EPB];                 // 32KB
    int t = threadIdx.x;
    int e0 = blockIdx.x * EPB;
    int ne = NE - e0; if (ne > EPB) ne = EPB;

    for (int i = t; i < NBUCK; i += 256) hist[i] = 0;
    __syncthreads();
    for (int i = t; i < ne; i += 256)
        atomicAdd(&hist[dst[e0 + i] >> 8], 1);
    __syncthreads();

    if (t < 64) {
        int run = 0;
        for (int c = 0; c < 7; ++c) {
            int i = c * 64 + t;
            int h = (i < NBUCK) ? hist[i] : 0;
            int v = h;
            for (int off = 1; off < 64; off <<= 1) {
                int tmp = __shfl_up(v, off, 64);
                if (t >= off) v += tmp;
            }
            if (i < NBUCK) scan_[i] = run + v - h;
            run += __shfl(v, 63, 64);
        }
        if (t == 0) scan_[NBUCK] = run;
    }
    __syncthreads();

    for (int i = t; i < NBUCK; i += 256) {
        int h = hist[i];
        gb[i] = h ? atomicAdd(&bcnt[i], h) : 0;
        curs[i] = scan_[i];
    }
    __syncthreads();

    for (int i = t; i < ne; i += 256) {
        int d = dst[e0 + i], s = src[e0 + i];
        int slot = atomicAdd(&curs[d >> 8], 1);
        lp[slot] = make_int2(s, d);
    }
    __syncthreads();

    for (int i = t; i < ne; i += 256) {
        int lo = 0, hi = NBUCK;
        while (hi - lo > 1) {
            int mid = (lo + hi) >> 1;
            if (scan_[mid] <= i) lo = mid; else hi = mid;
        }
        pairs[(size_t)lo * BCAP2 + gb[lo] + (i - scan_[lo])] = lp[i];
    }
}

// pass 2: one block per bucket -> col writes localized to one ~50KB region
__global__ __launch_bounds__(512) void fill2_kernel(
    const int* __restrict__ bcnt, const int2* __restrict__ pairs,
    int* __restrict__ cursor, int* __restrict__ col) {
    int b = blockIdx.x;
    int n = bcnt[b];
    const int2* seg = pairs + (size_t)b * BCAP2;
#pragma unroll 4
    for (int i = threadIdx.x; i < n; i += 512) {
        int2 sd = seg[i];
        int pos = atomicAdd(&cursor[sd.y], 1);
        col[pos] = sd.x;
    }
}

__global__ void zero_sentinel_kernel(_Float16* __restrict__ a, _Float16* __restrict__ b) {
    int t = threadIdx.x;                                // 128 threads
    a[(size_t)NN * HID + t] = (_Float16)0.f;
    b[(size_t)NN * HID + t] = (_Float16)0.f;
}

// ---------------- W prep: fp16 hi/lo split, MFMA B-fragment order ----------------

__global__ void wprep_init_kernel(const float* __restrict__ W,
                                  _Float16* __restrict__ Bhi, _Float16* __restrict__ Blo) {
    int t = blockIdx.x * 256 + threadIdx.x;     // 8 * 16 * 64 = 8192 threads
    if (t >= 8 * 16 * 64) return;
    int lane = t & 63, nkk = t >> 6;
    int n = nkk >> 4, kk = nkk & 15;
    int scol = n * 16 + (lane & 15);
    int sr0 = kk * 32 + (lane >> 4) * 8;
#pragma unroll
    for (int j = 0; j < 8; ++j) {
        float w = W[(size_t)(sr0 + j) * HID + scol];
        _Float16 hi = (_Float16)w;
        _Float16 lo = (_Float16)(w - (float)hi);
        Bhi[(size_t)t * 8 + j] = hi;
        Blo[(size_t)t * 8 + j] = lo;
    }
}

__global__ void wprep_layers_kernel(const float* __restrict__ WL,
                                    _Float16* __restrict__ Bhi, _Float16* __restrict__ Blo) {
    int t = blockIdx.x * 256 + threadIdx.x;     // 8 layers * 8*4*64 = 16384 threads
    if (t >= N_LAYERS * 8 * 4 * 64) return;
    int layer = t >> 11;
    int r = t & 2047;
    int lane = r & 63, nkk = r >> 6;
    int n = nkk >> 2, kk = nkk & 3;
    const float* W = WL + (size_t)layer * HID * HID;
    int scol = n * 16 + (lane & 15);
    int sr0 = kk * 32 + (lane >> 4) * 8;
#pragma unroll
    for (int j = 0; j < 8; ++j) {
        float w = W[(size_t)(sr0 + j) * HID + scol];
        _Float16 hi = (_Float16)w;
        _Float16 lo = (_Float16)(w - (float)hi);
        Bhi[(size_t)t * 8 + j] = hi;
        Blo[(size_t)t * 8 + j] = lo;
    }
}

// ---------------- init projection -> y = fp16(dinv*h0), x0 = fp16(h0) ----------------
// 64 rows/block, 1024 thr (16 waves -> 2 blocks/CU = 100% occupancy).
// wid<8: n=wid, m in {0,1}; wid>=8: n=wid-8, m in {2,3}.

__device__ inline int xsw(int row, int blk) {      // fp16 offset in [64][512] tile
    return row * 512 + ((blk ^ (row & 7)) << 3);
}

__global__ __launch_bounds__(1024) void init_mfma_kernel(
    const float* __restrict__ x, const h16x8* __restrict__ Bhi, const h16x8* __restrict__ Blo,
    const float* __restrict__ b, const float* __restrict__ dinv,
    _Float16* __restrict__ ycur, _Float16* __restrict__ x0h) {
    __shared__ _Float16 xs[64 * 512];           // 64KB, swizzled blocks of 8 fp16
    int t = threadIdx.x;
    int row0 = blockIdx.x * 64;

#pragma unroll
    for (int i = 0; i < 4; ++i) {               // linear 32B chunks: c = t + 1024*i
        int c = t + 1024 * i;
        int row = c >> 6, blk = c & 63;
        int grow = row0 + row; if (grow >= NN) grow = NN - 1;
        const float* p = x + (size_t)grow * IN_DIM + blk * 8;
        float4 v0 = *(const float4*)p;
        float4 v1 = *(const float4*)(p + 4);
        h16x8 h;
        h[0] = (_Float16)v0.x; h[1] = (_Float16)v0.y;
        h[2] = (_Float16)v0.z; h[3] = (_Float16)v0.w;
        h[4] = (_Float16)v1.x; h[5] = (_Float16)v1.y;
        h[6] = (_Float16)v1.z; h[7] = (_Float16)v1.w;
        *(h16x8*)&xs[xsw(row, blk)] = h;
    }
    __syncthreads();

    int lane = t & 63, wid = t >> 6;
    int nsel = wid & 7, mhalf = (wid >> 3) * 2;  // m offset 0 or 2
    int rsel = lane & 15, ksel = lane >> 4;

    f32x4 acc[2];
#pragma unroll
    for (int m = 0; m < 2; ++m) acc[m] = (f32x4){0.f, 0.f, 0.f, 0.f};

#pragma unroll
    for (int kk = 0; kk < 16; ++kk) {
        h16x8 bh = Bhi[(nsel * 16 + kk) * 64 + lane];
        h16x8 bl = Blo[(nsel * 16 + kk) * 64 + lane];
#pragma unroll
        for (int m = 0; m < 2; ++m) {
            h16x8 a = *(const h16x8*)&xs[xsw((mhalf + m) * 16 + rsel, kk * 4 + ksel)];
            acc[m] = __builtin_amdgcn_mfma_f32_16x16x32_f16(a, bh, acc[m], 0, 0, 0);
            acc[m] = __builtin_amdgcn_mfma_f32_16x16x32_f16(a, bl, acc[m], 0, 0, 0);
        }
    }

    int col = nsel * 16 + rsel;
    float bias = b[col];
#pragma unroll
    for (int m = 0; m < 2; ++m) {
#pragma unroll
        for (int r = 0; r < 4; ++r) {
            int row = row0 + (mhalf + m) * 16 + ksel * 4 + r;
            if (row < NN) {
                float v = acc[m][r] + bias;
                float di = dinv[row];
                ycur[(size_t)row * HID + col] = (_Float16)(di * v);
                x0h[(size_t)row * HID + col]  = (_Float16)v;
            }
        }
    }
}

// ---------------- fused layer: agg(y) -> LDS -> MFMA -> relu/residual -> y_out ----------------
// agg: each 16-lane GROUP owns one node (full 128-feat row across its lanes):
// no cross-lane reduce, 4 independent gather chains per wave, rows padded to 4.

__device__ inline int hsw(int row, int blk) {      // fp16 offset in [64][128] tile
    return row * 128 + ((blk ^ (row & 7)) << 3);
}

__global__ __launch_bounds__(512) void fused_layer_kernel(
    const _Float16* __restrict__ y, const _Float16* __restrict__ x0,
    const int* __restrict__ row_ptr, const int* __restrict__ col,
    const float* __restrict__ dinv,
    const h16x8* __restrict__ Bhi, const h16x8* __restrict__ Blo,
    float beta, _Float16* __restrict__ yout) {
    __shared__ _Float16 hs[64 * 128];
    int t = threadIdx.x;
    int lane = t & 63, wid = t >> 6;
    int node0 = blockIdx.x * 64;
    int g = lane >> 4, q = lane & 15;

    // preload this wave's n-tile B fragments (independent of agg)
    h16x8 bh[4], bl[4];
#pragma unroll
    for (int kk = 0; kk < 4; ++kk) {
        bh[kk] = Bhi[(wid * 4 + kk) * 64 + lane];
        bl[kk] = Blo[(wid * 4 + kk) * 64 + lane];
    }

    const h16x8* x8 = (const h16x8*)y;
#pragma unroll
    for (int j = 0; j < 2; ++j) {
        int ln = wid * 8 + j * 4 + g;              // local row owned by this group
        int node = node0 + ln;
        int valid = node < NN;
        int nd = valid ? node : 0;
        float di = dinv[nd];
        h16x8 sv = x8[(size_t)nd * 16 + q];
        h16x8 zv = ((const h16x8*)x0)[(size_t)nd * 16 + q];

        float acc[8];
#pragma unroll
        for (int jj = 0; jj < 8; ++jj) acc[jj] = 0.f;

        int p  = valid ? row_ptr[nd] : 0;
        int p1 = valid ? row_ptr[nd + 1] : 0;
#pragma unroll 2
        for (; p < p1; p += 4) {
            int4 c4 = *(const int4*)(col + p);     // uniform within group (broadcast)
            h16x8 v0 = x8[(size_t)c4.x * 16 + q];
            h16x8 v1 = x8[(size_t)c4.y * 16 + q];
            h16x8 v2 = x8[(size_t)c4.z * 16 + q];
            h16x8 v3 = x8[(size_t)c4.w * 16 + q];
#pragma unroll
            for (int jj = 0; jj < 8; ++jj)
                acc[jj] += ((float)v0[jj] + (float)v1[jj])
                         + ((float)v2[jj] + (float)v3[jj]);
        }

        h16x8 o16;
#pragma unroll
        for (int jj = 0; jj < 8; ++jj) {
            float s = acc[jj] + (float)sv[jj];     // + self y_d
            o16[jj] = (_Float16)(0.9f * (di * s) + 0.1f * (float)zv[jj]);
        }
        *(h16x8*)&hs[hsw(ln, q)] = o16;            // garbage rows (>NN) never stored
    }
    __syncthreads();

    // ---- MFMA phase: wave = n-tile wid, 4 m-tiles ----
    int rsel = lane & 15, ksel = lane >> 4;
    f32x4 acc[4];
#pragma unroll
    for (int m = 0; m < 4; ++m) acc[m] = (f32x4){0.f, 0.f, 0.f, 0.f};

#pragma unroll
    for (int m = 0; m < 4; ++m)
#pragma unroll
        for (int kk = 0; kk < 4; ++kk) {
            h16x8 a = *(const h16x8*)&hs[hsw(m * 16 + rsel, kk * 4 + ksel)];
            acc[m] = __builtin_amdgcn_mfma_f32_16x16x32_f16(a, bh[kk], acc[m], 0, 0, 0);
            acc[m] = __builtin_amdgcn_mfma_f32_16x16x32_f16(a, bl[kk], acc[m], 0, 0, 0);
        }

    float ob = 1.0f - beta;
    int colw = wid * 16 + rsel;
#pragma unroll
    for (int m = 0; m < 4; ++m) {
#pragma unroll
        for (int r = 0; r < 4; ++r) {
            int lr = m * 16 + ksel * 4 + r;
            int row = node0 + lr;
            if (row < NN) {
                float h = (float)hs[lr * 128 + (((colw >> 3) ^ (lr & 7)) << 3) + (colw & 7)];
                float v = ob * h + beta * acc[m][r];
                v = v > 0.f ? v : 0.f;
                yout[(size_t)row * HID + colw] = (_Float16)(dinv[row] * v);
            }
        }
    }
}

// ---------------- final projection: out = sqrt(deg+1) * (y . w) + b ----------------

__global__ __launch_bounds__(256) void final16_kernel(
    const _Float16* __restrict__ y, const int* __restrict__ deg,
    const float* __restrict__ Wout, const float* __restrict__ bout,
    float* __restrict__ out) {
    int node = blockIdx.x * 4 + (threadIdx.x >> 6);
    int lane = threadIdx.x & 63;
    h16x2 a = ((const h16x2*)y)[(size_t)node * 64 + lane];
    float2 w = ((const float2*)Wout)[lane];
    float v = (float)a[0] * w.x + (float)a[1] * w.y;
#pragma unroll
    for (int off = 32; off; off >>= 1) v += __shfl_down(v, off, 64);
    if (lane == 0) out[node] = v * sqrtf((float)(deg[node] + 1)) + bout[0];
}

// ---------------- host ----------------

extern "C" void kernel_launch(void* const* d_in, const int* in_sizes, int n_in,
                              void* d_out, int out_size, void* d_ws, size_t ws_size,
                              hipStream_t stream) {
    const float* x_in     = (const float*)d_in[0];
    const int*   ei       = (const int*)d_in[1];
    const float* W_in     = (const float*)d_in[3];
    const float* b_in     = (const float*)d_in[4];
    const float* W_layers = (const float*)d_in[5];
    const float* W_out    = (const float*)d_in[6];
    const float* b_out    = (const float*)d_in[7];
    float* out = (float*)d_out;

    const int* src = ei;
    const int* dst = ei + NE;

    char* ws = (char*)d_ws;
    size_t off = 0;
    auto alloc = [&](size_t bytes) {
        size_t p = off;
        off = (off + bytes + 255) & ~(size_t)255;
        return p;
    };
    int*   deg     = (int*)(ws + alloc((size_t)NN * 4));
    float* dinv    = (float*)(ws + alloc((size_t)NN * 4));
    int*   row_ptr = (int*)(ws + alloc((size_t)(NN + 1) * 4));
    int*   cursor  = (int*)(ws + alloc((size_t)NN * 4));
    int*   bsum    = (int*)(ws + alloc((size_t)NB * 4));
    int*   boff    = (int*)(ws + alloc((size_t)NB * 4));
    int*   bcnt    = (int*)(ws + alloc((size_t)NBUCK * 4));
    int*   col     = (int*)(ws + alloc((size_t)PADMAX * 4));
    size_t x0_off  = alloc((size_t)NN * HID * 2);
    _Float16* x0h  = (_Float16*)(ws + x0_off);
    int2*  pairs   = (int2*)(ws + x0_off);      // aliases x0h (14.4MB < 25.6MB):
                                                // CSR build completes before init_mfma
                                                // writes x0h (same stream)
    _Float16* bufA = (_Float16*)(ws + alloc((size_t)(NN + 16) * HID * 2));
    _Float16* bufB = (_Float16*)(ws + alloc((size_t)(NN + 16) * HID * 2));
    _Float16* Bhi0 = (_Float16*)(ws + alloc((size_t)IN_DIM * HID * 2));
    _Float16* Blo0 = (_Float16*)(ws + alloc((size_t)IN_DIM * HID * 2));
    _Float16* BhiL = (_Float16*)(ws + alloc((size_t)N_LAYERS * HID * HID * 2));
    _Float16* BloL = (_Float16*)(ws + alloc((size_t)N_LAYERS * HID * HID * 2));

    hipMemsetAsync(deg, 0, (size_t)NN * 4, stream);
    hipMemsetAsync(bcnt, 0, (size_t)NBUCK * 4, stream);

    deg_count_kernel<<<NE / 256, 256, 0, stream>>>(dst, deg);
    dinv_kernel<<<(NN + 255) / 256, 256, 0, stream>>>(deg, dinv);
    scan1_kernel<<<NB, 1024, 0, stream>>>(deg, bsum);
    scan2_kernel<<<1, 128, 0, stream>>>(bsum, boff, row_ptr);
    scan3_kernel<<<NB, 1024, 0, stream>>>(deg, boff, row_ptr, cursor);
    pad_kernel<<<(NN + 255) / 256, 256, 0, stream>>>(deg, row_ptr, col);
    bucket2_kernel<<<(NE + EPB - 1) / EPB, 256, 0, stream>>>(src, dst, bcnt, pairs);
    fill2_kernel<<<NBUCK, 512, 0, stream>>>(bcnt, pairs, cursor, col);
    zero_sentinel_kernel<<<1, 128, 0, stream>>>(bufA, bufB);

    wprep_init_kernel<<<32, 256, 0, stream>>>(W_in, Bhi0, Blo0);
    wprep_layers_kernel<<<64, 256, 0, stream>>>(W_layers, BhiL, BloL);

    init_mfma_kernel<<<(NN + 63) / 64, 1024, 0, stream>>>(
        x_in, (const h16x8*)Bhi0, (const h16x8*)Blo0, b_in, dinv, bufA, x0h);

    _Float16* cur = bufA;
    _Float16* nxt = bufB;
    for (int l = 0; l < N_LAYERS; ++l) {
        float beta = logf(0.5f / (float)(l + 1) + 1.0f);
        fused_layer_kernel<<<(NN + 63) / 64, 512, 0, stream>>>(
            cur, x0h, row_ptr, col, dinv,
            (const h16x8*)(BhiL + (size_t)l * HID * HID),
            (const h16x8*)(BloL + (size_t)l * HID * HID), beta, nxt);
        _Float16* tmp = cur; cur = nxt; nxt = tmp;
    }

    final16_kernel<<<NN / 4, 256, 0, stream>>>(cur, deg, W_out, b_out, out);
}

// Round 12
// 897.561 us; speedup vs baseline: 1.3815x; 1.0554x over previous
//
#include <hip/hip_runtime.h>
#include <math.h>

#define NN 100000
#define NE 1600000
#define IN_DIM 512
#define HID 128
#define N_LAYERS 8
#define NB 98               // ceil(NN/1024)
#define PADMAX 2000000      // NE + 3*NN + slack (rows padded to mult of 4)
#define NBUCK 391           // ceil(NN/256)
#define BCAP2 4608          // per-bucket capacity: mean 4096 + 8 sigma
#define EPB 4096            // edges per bucket2 block

typedef __attribute__((ext_vector_type(4))) float f32x4;
typedef __attribute__((ext_vector_type(8))) _Float16 h16x8;
typedef __attribute__((ext_vector_type(2))) _Float16 h16x2;

// ---------------- CSR build (rows padded to multiples of 4, col-only) ----------------

// pass 1: block-local counting sort of 4096 edges by dst-bucket (dst>>8).
// Also produces per-node degree (folded deg_count).
__global__ __launch_bounds__(256) void bucket2_kernel(
    const int* __restrict__ src, const int* __restrict__ dst,
    int* __restrict__ deg, int* __restrict__ bcnt, int2* __restrict__ pairs) {
    __shared__ int hist[NBUCK];
    __shared__ int scan_[NBUCK + 1];
    __shared__ int gb[NBUCK];
    __shared__ int curs[NBUCK];
    __shared__ int2 lp[EPB];                 // 32KB
    int t = threadIdx.x;
    int e0 = blockIdx.x * EPB;
    int ne = NE - e0; if (ne > EPB) ne = EPB;

    for (int i = t; i < NBUCK; i += 256) hist[i] = 0;
    __syncthreads();
    for (int i = t; i < ne; i += 256) {
        int d = dst[e0 + i];
        atomicAdd(&hist[d >> 8], 1);
        atomicAdd(&deg[d], 1);               // folded deg_count
    }
    __syncthreads();

    if (t < 64) {
        int run = 0;
        for (int c = 0; c < 7; ++c) {
            int i = c * 64 + t;
            int h = (i < NBUCK) ? hist[i] : 0;
            int v = h;
            for (int off = 1; off < 64; off <<= 1) {
                int tmp = __shfl_up(v, off, 64);
                if (t >= off) v += tmp;
            }
            if (i < NBUCK) scan_[i] = run + v - h;
            run += __shfl(v, 63, 64);
        }
        if (t == 0) scan_[NBUCK] = run;
    }
    __syncthreads();

    for (int i = t; i < NBUCK; i += 256) {
        int h = hist[i];
        gb[i] = h ? atomicAdd(&bcnt[i], h) : 0;
        curs[i] = scan_[i];
    }
    __syncthreads();

    for (int i = t; i < ne; i += 256) {
        int d = dst[e0 + i], s = src[e0 + i];
        int slot = atomicAdd(&curs[d >> 8], 1);
        lp[slot] = make_int2(s, d);
    }
    __syncthreads();

    for (int i = t; i < ne; i += 256) {
        int lo = 0, hi = NBUCK;
        while (hi - lo > 1) {
            int mid = (lo + hi) >> 1;
            if (scan_[mid] <= i) lo = mid; else hi = mid;
        }
        pairs[(size_t)lo * BCAP2 + gb[lo] + (i - scan_[lo])] = lp[i];
    }
}

__global__ void scan1_kernel(const int* __restrict__ deg, int* __restrict__ bsum) {
    __shared__ int s[16];
    int gi = blockIdx.x * 1024 + threadIdx.x;
    int d = (gi < NN) ? deg[gi] : 0;
    int r = (d + 3) & ~3;                                // padded capacity
    for (int off = 32; off; off >>= 1) r += __shfl_down(r, off, 64);
    if ((threadIdx.x & 63) == 0) s[threadIdx.x >> 6] = r;
    __syncthreads();
    if (threadIdx.x == 0) {
        int t = 0;
        for (int i = 0; i < 16; ++i) t += s[i];
        bsum[blockIdx.x] = t;
    }
}

// also zeroes sentinel rows of both y buffers (folded zero_sentinel)
__global__ void scan2_kernel(const int* __restrict__ bsum, int* __restrict__ boff,
                             int* __restrict__ row_ptr,
                             _Float16* __restrict__ sa, _Float16* __restrict__ sb) {
    __shared__ int s[128];
    int tid = threadIdx.x;
    sa[(size_t)NN * HID + tid] = (_Float16)0.f;
    sb[(size_t)NN * HID + tid] = (_Float16)0.f;
    int v = (tid < NB) ? bsum[tid] : 0;
    s[tid] = v;
    __syncthreads();
    for (int off = 1; off < 128; off <<= 1) {
        int t = (tid >= off) ? s[tid - off] : 0;
        __syncthreads();
        s[tid] += t;
        __syncthreads();
    }
    if (tid < NB) boff[tid] = s[tid] - v;   // exclusive
    if (tid == NB - 1) row_ptr[NN] = s[tid];
}

// also computes dinv (folded dinv_kernel)
__global__ void scan3_kernel(const int* __restrict__ deg, const int* __restrict__ boff,
                             int* __restrict__ row_ptr, int* __restrict__ cursor,
                             float* __restrict__ dinv) {
    __shared__ int s[1024];
    int tid = threadIdx.x;
    int gi = blockIdx.x * 1024 + tid;
    int d = (gi < NN) ? deg[gi] : 0;
    int v = (d + 3) & ~3;
    s[tid] = v;
    __syncthreads();
    for (int off = 1; off < 1024; off <<= 1) {
        int t = (tid >= off) ? s[tid - off] : 0;
        __syncthreads();
        s[tid] += t;
        __syncthreads();
    }
    if (gi < NN) {
        int o = boff[blockIdx.x] + s[tid] - v;
        row_ptr[gi] = o;
        cursor[gi]  = o;
        dinv[gi]    = rsqrtf((float)(d + 1));
    }
}

// pass 2: one block per bucket -> col writes localized to one ~50KB region.
// After filling, pads each row to a multiple of 4 (folded pad_kernel).
__global__ __launch_bounds__(512) void fill2_kernel(
    const int* __restrict__ bcnt, const int2* __restrict__ pairs,
    const int* __restrict__ row_ptr, int* __restrict__ cursor,
    int* __restrict__ col) {
    int b = blockIdx.x;
    int n = bcnt[b];
    const int2* seg = pairs + (size_t)b * BCAP2;
#pragma unroll 4
    for (int i = threadIdx.x; i < n; i += 512) {
        int2 sd = seg[i];
        int pos = atomicAdd(&cursor[sd.y], 1);
        col[pos] = sd.x;
    }
    __syncthreads();
    // pad: all edges for nodes in this bucket were written by THIS block
    int d0 = b * 256;
    int d1 = d0 + 256; if (d1 > NN) d1 = NN;
    for (int d = d0 + threadIdx.x; d < d1; d += 512) {
        int rp  = row_ptr[d];
        int end = cursor[d];                       // rp + deg
        int pend = rp + ((end - rp + 3) & ~3);
        for (int p = end; p < pend; ++p) col[p] = NN;  // sentinel: y[NN] == 0
    }
}

// ---------------- W prep: fp16 hi/lo split, MFMA B-fragment order ----------------

__global__ void wprep_init_kernel(const float* __restrict__ W,
                                  _Float16* __restrict__ Bhi, _Float16* __restrict__ Blo) {
    int t = blockIdx.x * 256 + threadIdx.x;     // 8 * 16 * 64 = 8192 threads
    if (t >= 8 * 16 * 64) return;
    int lane = t & 63, nkk = t >> 6;
    int n = nkk >> 4, kk = nkk & 15;
    int scol = n * 16 + (lane & 15);
    int sr0 = kk * 32 + (lane >> 4) * 8;
#pragma unroll
    for (int j = 0; j < 8; ++j) {
        float w = W[(size_t)(sr0 + j) * HID + scol];
        _Float16 hi = (_Float16)w;
        _Float16 lo = (_Float16)(w - (float)hi);
        Bhi[(size_t)t * 8 + j] = hi;
        Blo[(size_t)t * 8 + j] = lo;
    }
}

__global__ void wprep_layers_kernel(const float* __restrict__ WL,
                                    _Float16* __restrict__ Bhi, _Float16* __restrict__ Blo) {
    int t = blockIdx.x * 256 + threadIdx.x;     // 8 layers * 8*4*64 = 16384 threads
    if (t >= N_LAYERS * 8 * 4 * 64) return;
    int layer = t >> 11;
    int r = t & 2047;
    int lane = r & 63, nkk = r >> 6;
    int n = nkk >> 2, kk = nkk & 3;
    const float* W = WL + (size_t)layer * HID * HID;
    int scol = n * 16 + (lane & 15);
    int sr0 = kk * 32 + (lane >> 4) * 8;
#pragma unroll
    for (int j = 0; j < 8; ++j) {
        float w = W[(size_t)(sr0 + j) * HID + scol];
        _Float16 hi = (_Float16)w;
        _Float16 lo = (_Float16)(w - (float)hi);
        Bhi[(size_t)t * 8 + j] = hi;
        Blo[(size_t)t * 8 + j] = lo;
    }
}

// ---------------- init projection -> y = fp16(dinv*h0), x0 = fp16(0.1*h0) ----------------
// 64 rows/block, 1024 thr (16 waves -> 2 blocks/CU = 100% occupancy).

__device__ inline int xsw(int row, int blk) {      // fp16 offset in [64][512] tile
    return row * 512 + ((blk ^ (row & 7)) << 3);
}

__global__ __launch_bounds__(1024) void init_mfma_kernel(
    const float* __restrict__ x, const h16x8* __restrict__ Bhi, const h16x8* __restrict__ Blo,
    const float* __restrict__ b, const float* __restrict__ dinv,
    _Float16* __restrict__ ycur, _Float16* __restrict__ x0h) {
    __shared__ _Float16 xs[64 * 512];           // 64KB, swizzled blocks of 8 fp16
    int t = threadIdx.x;
    int row0 = blockIdx.x * 64;

#pragma unroll
    for (int i = 0; i < 4; ++i) {               // linear 32B chunks: c = t + 1024*i
        int c = t + 1024 * i;
        int row = c >> 6, blk = c & 63;
        int grow = row0 + row; if (grow >= NN) grow = NN - 1;
        const float* p = x + (size_t)grow * IN_DIM + blk * 8;
        float4 v0 = *(const float4*)p;
        float4 v1 = *(const float4*)(p + 4);
        h16x8 h;
        h[0] = (_Float16)v0.x; h[1] = (_Float16)v0.y;
        h[2] = (_Float16)v0.z; h[3] = (_Float16)v0.w;
        h[4] = (_Float16)v1.x; h[5] = (_Float16)v1.y;
        h[6] = (_Float16)v1.z; h[7] = (_Float16)v1.w;
        *(h16x8*)&xs[xsw(row, blk)] = h;
    }
    __syncthreads();

    int lane = t & 63, wid = t >> 6;
    int nsel = wid & 7, mhalf = (wid >> 3) * 2;  // m offset 0 or 2
    int rsel = lane & 15, ksel = lane >> 4;

    f32x4 acc[2];
#pragma unroll
    for (int m = 0; m < 2; ++m) acc[m] = (f32x4){0.f, 0.f, 0.f, 0.f};

#pragma unroll
    for (int kk = 0; kk < 16; ++kk) {
        h16x8 bh = Bhi[(nsel * 16 + kk) * 64 + lane];
        h16x8 bl = Blo[(nsel * 16 + kk) * 64 + lane];
#pragma unroll
        for (int m = 0; m < 2; ++m) {
            h16x8 a = *(const h16x8*)&xs[xsw((mhalf + m) * 16 + rsel, kk * 4 + ksel)];
            acc[m] = __builtin_amdgcn_mfma_f32_16x16x32_f16(a, bh, acc[m], 0, 0, 0);
            acc[m] = __builtin_amdgcn_mfma_f32_16x16x32_f16(a, bl, acc[m], 0, 0, 0);
        }
    }

    int col = nsel * 16 + rsel;
    float bias = b[col];
#pragma unroll
    for (int m = 0; m < 2; ++m) {
#pragma unroll
        for (int r = 0; r < 4; ++r) {
            int row = row0 + (mhalf + m) * 16 + ksel * 4 + r;
            if (row < NN) {
                float v = acc[m][r] + bias;
                float di = dinv[row];
                ycur[(size_t)row * HID + col] = (_Float16)(di * v);
                x0h[(size_t)row * HID + col]  = (_Float16)(0.1f * v);
            }
        }
    }
}

// ---------------- fused layer: agg(y) -> LDS -> MFMA -> relu/residual -> y_out ----------------
// agg: each 16-lane GROUP owns one node; x0 is pre-scaled by 0.1.

__device__ inline int hsw(int row, int blk) {      // fp16 offset in [64][128] tile
    return row * 128 + ((blk ^ (row & 7)) << 3);
}

__global__ __launch_bounds__(512) void fused_layer_kernel(
    const _Float16* __restrict__ y, const _Float16* __restrict__ x0,
    const int* __restrict__ row_ptr, const int* __restrict__ col,
    const float* __restrict__ dinv,
    const h16x8* __restrict__ Bhi, const h16x8* __restrict__ Blo,
    float beta, _Float16* __restrict__ yout) {
    __shared__ _Float16 hs[64 * 128];
    int t = threadIdx.x;
    int lane = t & 63, wid = t >> 6;
    int node0 = blockIdx.x * 64;
    int g = lane >> 4, q = lane & 15;

    // preload this wave's n-tile B fragments (independent of agg)
    h16x8 bh[4], bl[4];
#pragma unroll
    for (int kk = 0; kk < 4; ++kk) {
        bh[kk] = Bhi[(wid * 4 + kk) * 64 + lane];
        bl[kk] = Blo[(wid * 4 + kk) * 64 + lane];
    }

    const h16x8* x8 = (const h16x8*)y;
#pragma unroll
    for (int j = 0; j < 2; ++j) {
        int ln = wid * 8 + j * 4 + g;              // local row owned by this group
        int node = node0 + ln;
        int valid = node < NN;
        int nd = valid ? node : 0;
        float di = dinv[nd];
        h16x8 sv = x8[(size_t)nd * 16 + q];
        h16x8 zv = ((const h16x8*)x0)[(size_t)nd * 16 + q];   // pre-scaled 0.1*h0

        float acc[8];
#pragma unroll
        for (int jj = 0; jj < 8; ++jj) acc[jj] = 0.f;

        int p  = valid ? row_ptr[nd] : 0;
        int p1 = valid ? row_ptr[nd + 1] : 0;
#pragma unroll 2
        for (; p < p1; p += 4) {
            int4 c4 = *(const int4*)(col + p);     // uniform within group (broadcast)
            h16x8 v0 = x8[(size_t)c4.x * 16 + q];
            h16x8 v1 = x8[(size_t)c4.y * 16 + q];
            h16x8 v2 = x8[(size_t)c4.z * 16 + q];
            h16x8 v3 = x8[(size_t)c4.w * 16 + q];
#pragma unroll
            for (int jj = 0; jj < 8; ++jj)
                acc[jj] += ((float)v0[jj] + (float)v1[jj])
                         + ((float)v2[jj] + (float)v3[jj]);
        }

        float d9 = 0.9f * di;
        h16x8 o16;
#pragma unroll
        for (int jj = 0; jj < 8; ++jj) {
            float s = acc[jj] + (float)sv[jj];     // + self y_d
            o16[jj] = (_Float16)(d9 * s + (float)zv[jj]);
        }
        *(h16x8*)&hs[hsw(ln, q)] = o16;
    }
    __syncthreads();

    // ---- MFMA phase: wave = n-tile wid, 4 m-tiles ----
    int rsel = lane & 15, ksel = lane >> 4;
    f32x4 acc[4];
#pragma unroll
    for (int m = 0; m < 4; ++m) acc[m] = (f32x4){0.f, 0.f, 0.f, 0.f};

#pragma unroll
    for (int m = 0; m < 4; ++m)
#pragma unroll
        for (int kk = 0; kk < 4; ++kk) {
            h16x8 a = *(const h16x8*)&hs[hsw(m * 16 + rsel, kk * 4 + ksel)];
            acc[m] = __builtin_amdgcn_mfma_f32_16x16x32_f16(a, bh[kk], acc[m], 0, 0, 0);
            acc[m] = __builtin_amdgcn_mfma_f32_16x16x32_f16(a, bl[kk], acc[m], 0, 0, 0);
        }

    float ob = 1.0f - beta;
    int colw = wid * 16 + rsel;
#pragma unroll
    for (int m = 0; m < 4; ++m) {
#pragma unroll
        for (int r = 0; r < 4; ++r) {
            int lr = m * 16 + ksel * 4 + r;
            int row = node0 + lr;
            if (row < NN) {
                float h = (float)hs[lr * 128 + (((colw >> 3) ^ (lr & 7)) << 3) + (colw & 7)];
                float v = ob * h + beta * acc[m][r];
                v = v > 0.f ? v : 0.f;
                yout[(size_t)row * HID + colw] = (_Float16)(dinv[row] * v);
            }
        }
    }
}

// ---------------- final projection: out = sqrt(deg+1) * (y . w) + b ----------------

__global__ __launch_bounds__(256) void final16_kernel(
    const _Float16* __restrict__ y, const int* __restrict__ deg,
    const float* __restrict__ Wout, const float* __restrict__ bout,
    float* __restrict__ out) {
    int node = blockIdx.x * 4 + (threadIdx.x >> 6);
    int lane = threadIdx.x & 63;
    h16x2 a = ((const h16x2*)y)[(size_t)node * 64 + lane];
    float2 w = ((const float2*)Wout)[lane];
    float v = (float)a[0] * w.x + (float)a[1] * w.y;
#pragma unroll
    for (int off = 32; off; off >>= 1) v += __shfl_down(v, off, 64);
    if (lane == 0) out[node] = v * sqrtf((float)(deg[node] + 1)) + bout[0];
}

// ---------------- host ----------------

extern "C" void kernel_launch(void* const* d_in, const int* in_sizes, int n_in,
                              void* d_out, int out_size, void* d_ws, size_t ws_size,
                              hipStream_t stream) {
    const float* x_in     = (const float*)d_in[0];
    const int*   ei       = (const int*)d_in[1];
    const float* W_in     = (const float*)d_in[3];
    const float* b_in     = (const float*)d_in[4];
    const float* W_layers = (const float*)d_in[5];
    const float* W_out    = (const float*)d_in[6];
    const float* b_out    = (const float*)d_in[7];
    float* out = (float*)d_out;

    const int* src = ei;
    const int* dst = ei + NE;

    char* ws = (char*)d_ws;
    size_t off = 0;
    auto alloc = [&](size_t bytes) {
        size_t p = off;
        off = (off + bytes + 255) & ~(size_t)255;
        return p;
    };
    int*   deg     = (int*)(ws + alloc((size_t)NN * 4));
    int*   bcnt    = (int*)(ws + alloc((size_t)NBUCK * 4));   // adjacent to deg: one memset
    float* dinv    = (float*)(ws + alloc((size_t)NN * 4));
    int*   row_ptr = (int*)(ws + alloc((size_t)(NN + 1) * 4));
    int*   cursor  = (int*)(ws + alloc((size_t)NN * 4));
    int*   bsum    = (int*)(ws + alloc((size_t)NB * 4));
    int*   boff    = (int*)(ws + alloc((size_t)NB * 4));
    int*   col     = (int*)(ws + alloc((size_t)PADMAX * 4));
    size_t x0_off  = alloc((size_t)NN * HID * 2);
    _Float16* x0h  = (_Float16*)(ws + x0_off);
    int2*  pairs   = (int2*)(ws + x0_off);      // aliases x0h (14.4MB < 25.6MB):
                                                // CSR build completes before init_mfma
                                                // writes x0h (same stream)
    _Float16* bufA = (_Float16*)(ws + alloc((size_t)(NN + 16) * HID * 2));
    _Float16* bufB = (_Float16*)(ws + alloc((size_t)(NN + 16) * HID * 2));
    _Float16* Bhi0 = (_Float16*)(ws + alloc((size_t)IN_DIM * HID * 2));
    _Float16* Blo0 = (_Float16*)(ws + alloc((size_t)IN_DIM * HID * 2));
    _Float16* BhiL = (_Float16*)(ws + alloc((size_t)N_LAYERS * HID * HID * 2));
    _Float16* BloL = (_Float16*)(ws + alloc((size_t)N_LAYERS * HID * HID * 2));

    // one memset covers deg + (alignment gap) + bcnt
    hipMemsetAsync(deg, 0, (size_t)((char*)bcnt - (char*)deg) + (size_t)NBUCK * 4, stream);

    bucket2_kernel<<<(NE + EPB - 1) / EPB, 256, 0, stream>>>(src, dst, deg, bcnt, pairs);
    scan1_kernel<<<NB, 1024, 0, stream>>>(deg, bsum);
    scan2_kernel<<<1, 128, 0, stream>>>(bsum, boff, row_ptr, bufA, bufB);
    scan3_kernel<<<NB, 1024, 0, stream>>>(deg, boff, row_ptr, cursor, dinv);
    fill2_kernel<<<NBUCK, 512, 0, stream>>>(bcnt, pairs, row_ptr, cursor, col);

    wprep_init_kernel<<<32, 256, 0, stream>>>(W_in, Bhi0, Blo0);
    wprep_layers_kernel<<<64, 256, 0, stream>>>(W_layers, BhiL, BloL);

    init_mfma_kernel<<<(NN + 63) / 64, 1024, 0, stream>>>(
        x_in, (const h16x8*)Bhi0, (const h16x8*)Blo0, b_in, dinv, bufA, x0h);

    _Float16* cur = bufA;
    _Float16* nxt = bufB;
    for (int l = 0; l < N_LAYERS; ++l) {
        float beta = logf(0.5f / (float)(l + 1) + 1.0f);
        fused_layer_kernel<<<(NN + 63) / 64, 512, 0, stream>>>(
            cur, x0h, row_ptr, col, dinv,
            (const h16x8*)(BhiL + (size_t)l * HID * HID),
            (const h16x8*)(BloL + (size_t)l * HID * HID), beta, nxt);
        _Float16* tmp = cur; cur = nxt; nxt = tmp;
    }

    final16_kernel<<<NN / 4, 256, 0, stream>>>(cur, deg, W_out, b_out, out);
}

// Round 13
// 850.049 us; speedup vs baseline: 1.4587x; 1.0559x over previous
//
#include <hip/hip_runtime.h>
#include <math.h>

#define NN 100000
#define NE 1600000
#define IN_DIM 512
#define HID 128
#define N_LAYERS 8
#define NB 98               // ceil(NN/1024)
#define PADMAX 2000000      // NE + 3*NN + slack (rows padded to mult of 4)
#define NBUCK 391           // ceil(NN/256)
#define BCAP2 4608          // per-bucket capacity: mean 4096 + 8 sigma
#define EPB 4096            // edges per bucket2 block

typedef __attribute__((ext_vector_type(4))) float f32x4;
typedef __attribute__((ext_vector_type(8))) _Float16 h16x8;
typedef __attribute__((ext_vector_type(2))) _Float16 h16x2;

// ---------------- CSR build (rows padded to multiples of 4, col-only) ----------------
// pairs entries packed: (d & 255) << 17 | src   (src < 2^17, 25 bits total)

__global__ __launch_bounds__(256) void bucket2_kernel(
    const int* __restrict__ src, const int* __restrict__ dst,
    int* __restrict__ deg, int* __restrict__ bcnt, int* __restrict__ pairs) {
    __shared__ int hist[NBUCK];
    __shared__ int scan_[NBUCK + 1];
    __shared__ int gb[NBUCK];
    __shared__ int curs[NBUCK];
    __shared__ int lp[EPB];                  // 16KB packed
    int t = threadIdx.x;
    int e0 = blockIdx.x * EPB;
    int ne = NE - e0; if (ne > EPB) ne = EPB;

    for (int i = t; i < NBUCK; i += 256) hist[i] = 0;
    __syncthreads();
    for (int i = t; i < ne; i += 256) {
        int d = dst[e0 + i];
        atomicAdd(&hist[d >> 8], 1);
        atomicAdd(&deg[d], 1);               // folded deg_count
    }
    __syncthreads();

    if (t < 64) {
        int run = 0;
        for (int c = 0; c < 7; ++c) {
            int i = c * 64 + t;
            int h = (i < NBUCK) ? hist[i] : 0;
            int v = h;
            for (int off = 1; off < 64; off <<= 1) {
                int tmp = __shfl_up(v, off, 64);
                if (t >= off) v += tmp;
            }
            if (i < NBUCK) scan_[i] = run + v - h;
            run += __shfl(v, 63, 64);
        }
        if (t == 0) scan_[NBUCK] = run;
    }
    __syncthreads();

    for (int i = t; i < NBUCK; i += 256) {
        int h = hist[i];
        gb[i] = h ? atomicAdd(&bcnt[i], h) : 0;
        curs[i] = scan_[i];
    }
    __syncthreads();

    for (int i = t; i < ne; i += 256) {
        int d = dst[e0 + i], s = src[e0 + i];
        int slot = atomicAdd(&curs[d >> 8], 1);
        lp[slot] = ((d & 255) << 17) | s;
    }
    __syncthreads();

    for (int i = t; i < ne; i += 256) {
        int lo = 0, hi = NBUCK;
        while (hi - lo > 1) {
            int mid = (lo + hi) >> 1;
            if (scan_[mid] <= i) lo = mid; else hi = mid;
        }
        pairs[(size_t)lo * BCAP2 + gb[lo] + (i - scan_[lo])] = lp[i];
    }
}

__global__ void scan1_kernel(const int* __restrict__ deg, int* __restrict__ bsum) {
    __shared__ int s[16];
    int gi = blockIdx.x * 1024 + threadIdx.x;
    int d = (gi < NN) ? deg[gi] : 0;
    int r = (d + 3) & ~3;                                // padded capacity
    for (int off = 32; off; off >>= 1) r += __shfl_down(r, off, 64);
    if ((threadIdx.x & 63) == 0) s[threadIdx.x >> 6] = r;
    __syncthreads();
    if (threadIdx.x == 0) {
        int t = 0;
        for (int i = 0; i < 16; ++i) t += s[i];
        bsum[blockIdx.x] = t;
    }
}

// also zeroes sentinel rows of both y buffers (folded zero_sentinel)
__global__ void scan2_kernel(const int* __restrict__ bsum, int* __restrict__ boff,
                             int* __restrict__ row_ptr,
                             _Float16* __restrict__ sa, _Float16* __restrict__ sb) {
    __shared__ int s[128];
    int tid = threadIdx.x;
    sa[(size_t)NN * HID + tid] = (_Float16)0.f;
    sb[(size_t)NN * HID + tid] = (_Float16)0.f;
    int v = (tid < NB) ? bsum[tid] : 0;
    s[tid] = v;
    __syncthreads();
    for (int off = 1; off < 128; off <<= 1) {
        int t = (tid >= off) ? s[tid - off] : 0;
        __syncthreads();
        s[tid] += t;
        __syncthreads();
    }
    if (tid < NB) boff[tid] = s[tid] - v;   // exclusive
    if (tid == NB - 1) row_ptr[NN] = s[tid];
}

// also computes dinv (folded dinv_kernel)
__global__ void scan3_kernel(const int* __restrict__ deg, const int* __restrict__ boff,
                             int* __restrict__ row_ptr, float* __restrict__ dinv) {
    __shared__ int s[1024];
    int tid = threadIdx.x;
    int gi = blockIdx.x * 1024 + tid;
    int d = (gi < NN) ? deg[gi] : 0;
    int v = (d + 3) & ~3;
    s[tid] = v;
    __syncthreads();
    for (int off = 1; off < 1024; off <<= 1) {
        int t = (tid >= off) ? s[tid - off] : 0;
        __syncthreads();
        s[tid] += t;
        __syncthreads();
    }
    if (gi < NN) {
        row_ptr[gi] = boff[blockIdx.x] + s[tid] - v;
        dinv[gi]    = rsqrtf((float)(d + 1));
    }
}

// pass 2: one block per bucket; LDS cursors (bucket-exclusive); pads rows to mult 4.
__global__ __launch_bounds__(512) void fill2_kernel(
    const int* __restrict__ bcnt, const int* __restrict__ pairs,
    const int* __restrict__ row_ptr, int* __restrict__ col) {
    __shared__ int lcur[256];
    int b = blockIdx.x;
    int d0 = b * 256;
    for (int i = threadIdx.x; i < 256; i += 512) {
        int d = d0 + i;
        lcur[i] = (d < NN) ? row_ptr[d] : 0;
    }
    __syncthreads();
    int n = bcnt[b];
    const int* seg = pairs + (size_t)b * BCAP2;
#pragma unroll 4
    for (int i = threadIdx.x; i < n; i += 512) {
        int v = seg[i];
        int pos = atomicAdd(&lcur[v >> 17], 1);
        col[pos] = v & 0x1FFFF;
    }
    __syncthreads();
    for (int i = threadIdx.x; i < 256; i += 512) {
        int d = d0 + i;
        if (d < NN) {
            int rp = row_ptr[d];
            int end = lcur[i];                         // rp + deg
            int pend = rp + ((end - rp + 3) & ~3);
            for (int p = end; p < pend; ++p) col[p] = NN;  // sentinel: y[NN] == 0
        }
    }
}

// ---------------- W prep (merged): fp16 hi/lo split, MFMA B-fragment order ----------------

__global__ void wprep_kernel(const float* __restrict__ W_in, const float* __restrict__ WL,
                             _Float16* __restrict__ Bhi0, _Float16* __restrict__ Blo0,
                             _Float16* __restrict__ BhiL, _Float16* __restrict__ BloL) {
    int bid = blockIdx.x;
    if (bid < 32) {                              // init W: 8192 threads
        int t = bid * 256 + threadIdx.x;
        int lane = t & 63, nkk = t >> 6;
        int n = nkk >> 4, kk = nkk & 15;
        int scol = n * 16 + (lane & 15);
        int sr0 = kk * 32 + (lane >> 4) * 8;
#pragma unroll
        for (int j = 0; j < 8; ++j) {
            float w = W_in[(size_t)(sr0 + j) * HID + scol];
            _Float16 hi = (_Float16)w;
            _Float16 lo = (_Float16)(w - (float)hi);
            Bhi0[(size_t)t * 8 + j] = hi;
            Blo0[(size_t)t * 8 + j] = lo;
        }
    } else {                                     // layer Ws: 16384 threads
        int t = (bid - 32) * 256 + threadIdx.x;
        int layer = t >> 11;
        int r = t & 2047;
        int lane = r & 63, nkk = r >> 6;
        int n = nkk >> 2, kk = nkk & 3;
        const float* W = WL + (size_t)layer * HID * HID;
        int scol = n * 16 + (lane & 15);
        int sr0 = kk * 32 + (lane >> 4) * 8;
#pragma unroll
        for (int j = 0; j < 8; ++j) {
            float w = W[(size_t)(sr0 + j) * HID + scol];
            _Float16 hi = (_Float16)w;
            _Float16 lo = (_Float16)(w - (float)hi);
            BhiL[(size_t)t * 8 + j] = hi;
            BloL[(size_t)t * 8 + j] = lo;
        }
    }
}

// ---------------- init projection -> y = fp16(dinv*h0), x0 = fp16(0.1*h0) ----------------
// 32 rows/block, 512 thr, LDS 32KB -> 4 blocks/CU: staging/compute phases desync
// across blocks (fixes the lockstep barrier-drain of the 64-row version).

__device__ inline int xsw(int row, int blk) {      // fp16 offset in [rows][512] tile
    return row * 512 + ((blk ^ (row & 7)) << 3);
}

__global__ __launch_bounds__(512) void init_mfma_kernel(
    const float* __restrict__ x, const h16x8* __restrict__ Bhi, const h16x8* __restrict__ Blo,
    const float* __restrict__ b, const float* __restrict__ dinv,
    _Float16* __restrict__ ycur, _Float16* __restrict__ x0h) {
    __shared__ _Float16 xs[32 * 512];           // 32KB swizzled
    int t = threadIdx.x;
    int row0 = blockIdx.x * 32;                 // NN % 32 == 0: no tails anywhere

#pragma unroll
    for (int i = 0; i < 4; ++i) {               // linear 32B chunks: c = t + 512*i
        int c = t + 512 * i;
        int row = c >> 6, blk = c & 63;
        const float* p = x + (size_t)(row0 + row) * IN_DIM + blk * 8;
        float4 v0 = *(const float4*)p;
        float4 v1 = *(const float4*)(p + 4);
        h16x8 h;
        h[0] = (_Float16)v0.x; h[1] = (_Float16)v0.y;
        h[2] = (_Float16)v0.z; h[3] = (_Float16)v0.w;
        h[4] = (_Float16)v1.x; h[5] = (_Float16)v1.y;
        h[6] = (_Float16)v1.z; h[7] = (_Float16)v1.w;
        *(h16x8*)&xs[xsw(row, blk)] = h;
    }
    __syncthreads();

    int lane = t & 63, wid = t >> 6;            // wave = n-tile, m = 0..1
    int rsel = lane & 15, ksel = lane >> 4;

    f32x4 acc[2];
#pragma unroll
    for (int m = 0; m < 2; ++m) acc[m] = (f32x4){0.f, 0.f, 0.f, 0.f};

#pragma unroll
    for (int kk = 0; kk < 16; ++kk) {
        h16x8 bh = Bhi[(wid * 16 + kk) * 64 + lane];
        h16x8 bl = Blo[(wid * 16 + kk) * 64 + lane];
#pragma unroll
        for (int m = 0; m < 2; ++m) {
            h16x8 a = *(const h16x8*)&xs[xsw(m * 16 + rsel, kk * 4 + ksel)];
            acc[m] = __builtin_amdgcn_mfma_f32_16x16x32_f16(a, bh, acc[m], 0, 0, 0);
            acc[m] = __builtin_amdgcn_mfma_f32_16x16x32_f16(a, bl, acc[m], 0, 0, 0);
        }
    }

    int col = wid * 16 + rsel;
    float bias = b[col];
#pragma unroll
    for (int m = 0; m < 2; ++m) {
#pragma unroll
        for (int r = 0; r < 4; ++r) {
            int row = row0 + m * 16 + ksel * 4 + r;
            float v = acc[m][r] + bias;
            float di = dinv[row];
            ycur[(size_t)row * HID + col] = (_Float16)(di * v);
            x0h[(size_t)row * HID + col]  = (_Float16)(0.1f * v);
        }
    }
}

// ---------------- fused layer: agg(y) -> LDS -> MFMA -> relu/residual -> y_out ----------------
// LAST=1: fold final projection (sqrt(deg+1)*dinv == 1 -> out = sum v*w + b), skip yout.

__device__ inline int hsw(int row, int blk) {      // fp16 offset in [64][128] tile
    return row * 128 + ((blk ^ (row & 7)) << 3);
}

template <int LAST>
__global__ __launch_bounds__(512) void fused_layer_kernel(
    const _Float16* __restrict__ y, const _Float16* __restrict__ x0,
    const int* __restrict__ row_ptr, const int* __restrict__ col,
    const float* __restrict__ dinv,
    const h16x8* __restrict__ Bhi, const h16x8* __restrict__ Blo,
    float beta, _Float16* __restrict__ yout,
    const float* __restrict__ Wout, const float* __restrict__ bout,
    float* __restrict__ out) {
    __shared__ _Float16 hs[64 * 128];
    int t = threadIdx.x;
    int lane = t & 63, wid = t >> 6;
    int node0 = blockIdx.x * 64;
    int g = lane >> 4, q = lane & 15;

    // preload this wave's n-tile B fragments (independent of agg)
    h16x8 bh[4], bl[4];
#pragma unroll
    for (int kk = 0; kk < 4; ++kk) {
        bh[kk] = Bhi[(wid * 4 + kk) * 64 + lane];
        bl[kk] = Blo[(wid * 4 + kk) * 64 + lane];
    }

    const h16x8* x8 = (const h16x8*)y;
#pragma unroll
    for (int j = 0; j < 2; ++j) {
        int ln = wid * 8 + j * 4 + g;              // local row owned by this group
        int node = node0 + ln;
        int valid = node < NN;
        int nd = valid ? node : 0;
        float di = dinv[nd];
        h16x8 sv = x8[(size_t)nd * 16 + q];
        h16x8 zv = ((const h16x8*)x0)[(size_t)nd * 16 + q];   // pre-scaled 0.1*h0

        float acc[8];
#pragma unroll
        for (int jj = 0; jj < 8; ++jj) acc[jj] = 0.f;

        int p  = valid ? row_ptr[nd] : 0;
        int p1 = valid ? row_ptr[nd + 1] : 0;
#pragma unroll 2
        for (; p < p1; p += 4) {
            int4 c4 = *(const int4*)(col + p);     // uniform within group (broadcast)
            h16x8 v0 = x8[(size_t)c4.x * 16 + q];
            h16x8 v1 = x8[(size_t)c4.y * 16 + q];
            h16x8 v2 = x8[(size_t)c4.z * 16 + q];
            h16x8 v3 = x8[(size_t)c4.w * 16 + q];
#pragma unroll
            for (int jj = 0; jj < 8; ++jj)
                acc[jj] += ((float)v0[jj] + (float)v1[jj])
                         + ((float)v2[jj] + (float)v3[jj]);
        }

        float d9 = 0.9f * di;
        h16x8 o16;
#pragma unroll
        for (int jj = 0; jj < 8; ++jj) {
            float s = acc[jj] + (float)sv[jj];     // + self y_d
            o16[jj] = (_Float16)(d9 * s + (float)zv[jj]);
        }
        *(h16x8*)&hs[hsw(ln, q)] = o16;
    }
    __syncthreads();

    // ---- MFMA phase: wave = n-tile wid, 4 m-tiles ----
    int rsel = lane & 15, ksel = lane >> 4;
    f32x4 acc[4];
#pragma unroll
    for (int m = 0; m < 4; ++m) acc[m] = (f32x4){0.f, 0.f, 0.f, 0.f};

#pragma unroll
    for (int m = 0; m < 4; ++m)
#pragma unroll
        for (int kk = 0; kk < 4; ++kk) {
            h16x8 a = *(const h16x8*)&hs[hsw(m * 16 + rsel, kk * 4 + ksel)];
            acc[m] = __builtin_amdgcn_mfma_f32_16x16x32_f16(a, bh[kk], acc[m], 0, 0, 0);
            acc[m] = __builtin_amdgcn_mfma_f32_16x16x32_f16(a, bl[kk], acc[m], 0, 0, 0);
        }

    float ob = 1.0f - beta;
    int colw = wid * 16 + rsel;

    if constexpr (!LAST) {
#pragma unroll
        for (int m = 0; m < 4; ++m) {
#pragma unroll
            for (int r = 0; r < 4; ++r) {
                int lr = m * 16 + ksel * 4 + r;
                int row = node0 + lr;
                if (row < NN) {
                    float h = (float)hs[lr * 128 + (((colw >> 3) ^ (lr & 7)) << 3) + (colw & 7)];
                    float v = ob * h + beta * acc[m][r];
                    v = v > 0.f ? v : 0.f;
                    yout[(size_t)row * HID + colw] = (_Float16)(dinv[row] * v);
                }
            }
        }
    } else {
        __shared__ float red[64][9];               // [row][wave], padded
        float wv = Wout[colw];
#pragma unroll
        for (int m = 0; m < 4; ++m) {
#pragma unroll
            for (int r = 0; r < 4; ++r) {
                int lr = m * 16 + ksel * 4 + r;
                float h = (float)hs[lr * 128 + (((colw >> 3) ^ (lr & 7)) << 3) + (colw & 7)];
                float v = ob * h + beta * acc[m][r];
                v = v > 0.f ? v : 0.f;
                float pp = v * wv;                 // partial over this wave's 16 cols
                pp += __shfl_xor(pp, 1, 64);
                pp += __shfl_xor(pp, 2, 64);
                pp += __shfl_xor(pp, 4, 64);
                pp += __shfl_xor(pp, 8, 64);
                if (rsel == 0) red[lr][wid] = pp;
            }
        }
        __syncthreads();
        if (t < 64) {
            int row = node0 + t;
            if (row < NN) {
                float s = bout[0];
#pragma unroll
                for (int w = 0; w < 8; ++w) s += red[t][w];
                out[row] = s;
            }
        }
    }
}

// ---------------- host ----------------

extern "C" void kernel_launch(void* const* d_in, const int* in_sizes, int n_in,
                              void* d_out, int out_size, void* d_ws, size_t ws_size,
                              hipStream_t stream) {
    const float* x_in     = (const float*)d_in[0];
    const int*   ei       = (const int*)d_in[1];
    const float* W_in     = (const float*)d_in[3];
    const float* b_in     = (const float*)d_in[4];
    const float* W_layers = (const float*)d_in[5];
    const float* W_out    = (const float*)d_in[6];
    const float* b_out    = (const float*)d_in[7];
    float* out = (float*)d_out;

    const int* src = ei;
    const int* dst = ei + NE;

    char* ws = (char*)d_ws;
    size_t off = 0;
    auto alloc = [&](size_t bytes) {
        size_t p = off;
        off = (off + bytes + 255) & ~(size_t)255;
        return p;
    };
    int*   deg     = (int*)(ws + alloc((size_t)NN * 4));
    int*   bcnt    = (int*)(ws + alloc((size_t)NBUCK * 4));   // adjacent to deg: one memset
    float* dinv    = (float*)(ws + alloc((size_t)NN * 4));
    int*   row_ptr = (int*)(ws + alloc((size_t)(NN + 1) * 4));
    int*   bsum    = (int*)(ws + alloc((size_t)NB * 4));
    int*   boff    = (int*)(ws + alloc((size_t)NB * 4));
    int*   col     = (int*)(ws + alloc((size_t)PADMAX * 4));
    size_t x0_off  = alloc((size_t)NN * HID * 2);
    _Float16* x0h  = (_Float16*)(ws + x0_off);
    int*   pairs   = (int*)(ws + x0_off);       // aliases x0h (7.2MB < 25.6MB):
                                                // CSR build completes before init_mfma
                                                // writes x0h (same stream)
    _Float16* bufA = (_Float16*)(ws + alloc((size_t)(NN + 16) * HID * 2));
    _Float16* bufB = (_Float16*)(ws + alloc((size_t)(NN + 16) * HID * 2));
    _Float16* Bhi0 = (_Float16*)(ws + alloc((size_t)IN_DIM * HID * 2));
    _Float16* Blo0 = (_Float16*)(ws + alloc((size_t)IN_DIM * HID * 2));
    _Float16* BhiL = (_Float16*)(ws + alloc((size_t)N_LAYERS * HID * HID * 2));
    _Float16* BloL = (_Float16*)(ws + alloc((size_t)N_LAYERS * HID * HID * 2));

    // one memset covers deg + (alignment gap) + bcnt
    hipMemsetAsync(deg, 0, (size_t)((char*)bcnt - (char*)deg) + (size_t)NBUCK * 4, stream);

    bucket2_kernel<<<(NE + EPB - 1) / EPB, 256, 0, stream>>>(src, dst, deg, bcnt, pairs);
    scan1_kernel<<<NB, 1024, 0, stream>>>(deg, bsum);
    scan2_kernel<<<1, 128, 0, stream>>>(bsum, boff, row_ptr, bufA, bufB);
    scan3_kernel<<<NB, 1024, 0, stream>>>(deg, boff, row_ptr, dinv);
    fill2_kernel<<<NBUCK, 512, 0, stream>>>(bcnt, pairs, row_ptr, col);

    wprep_kernel<<<96, 256, 0, stream>>>(W_in, W_layers, Bhi0, Blo0, BhiL, BloL);

    init_mfma_kernel<<<NN / 32, 512, 0, stream>>>(
        x_in, (const h16x8*)Bhi0, (const h16x8*)Blo0, b_in, dinv, bufA, x0h);

    _Float16* cur = bufA;
    _Float16* nxt = bufB;
    for (int l = 0; l < N_LAYERS - 1; ++l) {
        float beta = logf(0.5f / (float)(l + 1) + 1.0f);
        fused_layer_kernel<0><<<(NN + 63) / 64, 512, 0, stream>>>(
            cur, x0h, row_ptr, col, dinv,
            (const h16x8*)(BhiL + (size_t)l * HID * HID),
            (const h16x8*)(BloL + (size_t)l * HID * HID), beta, nxt,
            nullptr, nullptr, nullptr);
        _Float16* tmp = cur; cur = nxt; nxt = tmp;
    }
    {
        float beta = logf(0.5f / (float)N_LAYERS + 1.0f);
        fused_layer_kernel<1><<<(NN + 63) / 64, 512, 0, stream>>>(
            cur, x0h, row_ptr, col, dinv,
            (const h16x8*)(BhiL + (size_t)(N_LAYERS - 1) * HID * HID),
            (const h16x8*)(BloL + (size_t)(N_LAYERS - 1) * HID * HID), beta, nxt,
            W_out, b_out, out);
    }
}

// Round 14
// 832.079 us; speedup vs baseline: 1.4902x; 1.0216x over previous
//
#include <hip/hip_runtime.h>
#include <math.h>

#define NN 100000
#define NE 1600000
#define IN_DIM 512
#define HID 128
#define N_LAYERS 8
#define NB 98               // ceil(NN/1024)
#define PADMAX 2000000      // NE + 3*NN + slack (rows padded to mult of 4)
#define NBUCK 391           // ceil(NN/256)
#define BCAP2 4608          // per-bucket capacity: mean 4096 + 8 sigma
#define EPB 4096            // edges per bucket2 block

typedef __attribute__((ext_vector_type(4))) float f32x4;
typedef __attribute__((ext_vector_type(8))) _Float16 h16x8;
typedef __attribute__((ext_vector_type(2))) _Float16 h16x2;

// ---------------- CSR build (rows padded to multiples of 4, col-only) ----------------
// pairs entries packed: (d & 255) << 17 | src   (src < 2^17, 25 bits total)

// pass 1: block-local counting sort of 4096 edges by dst-bucket (dst>>8).
// Edges cached in LDS (single global read); bucket id memoized in lbuck
// (replaces per-edge binary search); also accumulates deg.
__global__ __launch_bounds__(512) void bucket2_kernel(
    const int* __restrict__ src, const int* __restrict__ dst,
    int* __restrict__ deg, int* __restrict__ bcnt, int* __restrict__ pairs) {
    __shared__ int2 edg[EPB];                // 32KB
    __shared__ int lp[EPB];                  // 16KB packed
    __shared__ unsigned short lbuck[EPB];    // 8KB
    __shared__ int hist[NBUCK];
    __shared__ int scan_[NBUCK + 1];
    __shared__ int gb[NBUCK];
    __shared__ int curs[NBUCK];
    int t = threadIdx.x;
    int e0 = blockIdx.x * EPB;
    int ne = NE - e0; if (ne > EPB) ne = EPB;

    for (int i = t; i < NBUCK; i += 512) hist[i] = 0;
    __syncthreads();
    for (int i = t; i < ne; i += 512) {
        int s = src[e0 + i], d = dst[e0 + i];
        edg[i] = make_int2(s, d);
        atomicAdd(&hist[d >> 8], 1);
        atomicAdd(&deg[d], 1);               // folded deg_count
    }
    __syncthreads();

    if (t < 64) {                            // exclusive scan over 391 buckets
        int run = 0;
        for (int c = 0; c < 7; ++c) {
            int i = c * 64 + t;
            int h = (i < NBUCK) ? hist[i] : 0;
            int v = h;
            for (int off = 1; off < 64; off <<= 1) {
                int tmp = __shfl_up(v, off, 64);
                if (t >= off) v += tmp;
            }
            if (i < NBUCK) scan_[i] = run + v - h;
            run += __shfl(v, 63, 64);
        }
        if (t == 0) scan_[NBUCK] = run;
    }
    __syncthreads();

    for (int i = t; i < NBUCK; i += 512) {
        int h = hist[i];
        gb[i] = h ? atomicAdd(&bcnt[i], h) : 0;
        curs[i] = scan_[i];
    }
    __syncthreads();

    for (int i = t; i < ne; i += 512) {      // stable binning into LDS
        int2 sd = edg[i];
        int b = sd.y >> 8;
        int slot = atomicAdd(&curs[b], 1);
        lp[slot] = ((sd.y & 255) << 17) | sd.x;
        lbuck[slot] = (unsigned short)b;
    }
    __syncthreads();

    for (int i = t; i < ne; i += 512) {      // coalesced chunk write-out
        int b = lbuck[i];
        pairs[(size_t)b * BCAP2 + gb[b] + (i - scan_[b])] = lp[i];
    }
}

// per-1024-node padded sums; block 0 also zeroes sentinel rows of both y buffers
__global__ void scan1_kernel(const int* __restrict__ deg, int* __restrict__ bsum,
                             _Float16* __restrict__ sa, _Float16* __restrict__ sb) {
    __shared__ int s[16];
    if (blockIdx.x == 0 && threadIdx.x < 128) {
        sa[(size_t)NN * HID + threadIdx.x] = (_Float16)0.f;
        sb[(size_t)NN * HID + threadIdx.x] = (_Float16)0.f;
    }
    int gi = blockIdx.x * 1024 + threadIdx.x;
    int d = (gi < NN) ? deg[gi] : 0;
    int r = (d + 3) & ~3;                                // padded capacity
    for (int off = 32; off; off >>= 1) r += __shfl_down(r, off, 64);
    if ((threadIdx.x & 63) == 0) s[threadIdx.x >> 6] = r;
    __syncthreads();
    if (threadIdx.x == 0) {
        int t = 0;
        for (int i = 0; i < 16; ++i) t += s[i];
        bsum[blockIdx.x] = t;
    }
}

// row_ptr + dinv; each block computes its own base from bsum (scan2 folded away)
__global__ void scan3_kernel(const int* __restrict__ deg, const int* __restrict__ bsum,
                             int* __restrict__ row_ptr, float* __restrict__ dinv) {
    __shared__ int s[1024];
    __shared__ int base_s;
    int tid = threadIdx.x;
    int bid = blockIdx.x;
    if (tid < 64) {
        int v = 0;
#pragma unroll
        for (int c = 0; c < 2; ++c) {
            int i = c * 64 + tid;
            if (i < NB && i < bid) v += bsum[i];
        }
        for (int off = 32; off; off >>= 1) v += __shfl_down(v, off, 64);
        if (tid == 0) base_s = v;
    }
    int gi = bid * 1024 + tid;
    int d = (gi < NN) ? deg[gi] : 0;
    int v = (d + 3) & ~3;
    s[tid] = v;
    __syncthreads();
    for (int off = 1; off < 1024; off <<= 1) {
        int t = (tid >= off) ? s[tid - off] : 0;
        __syncthreads();
        s[tid] += t;
        __syncthreads();
    }
    if (gi < NN) {
        row_ptr[gi] = base_s + s[tid] - v;
        dinv[gi]    = rsqrtf((float)(d + 1));
    }
    if (bid == NB - 1 && tid == 1023) row_ptr[NN] = base_s + s[tid];
}

// pass 2: one block per bucket; LDS cursors (bucket-exclusive); pads rows to mult 4.
__global__ __launch_bounds__(512) void fill2_kernel(
    const int* __restrict__ bcnt, const int* __restrict__ pairs,
    const int* __restrict__ row_ptr, int* __restrict__ col) {
    __shared__ int lcur[256];
    int b = blockIdx.x;
    int d0 = b * 256;
    for (int i = threadIdx.x; i < 256; i += 512) {
        int d = d0 + i;
        lcur[i] = (d < NN) ? row_ptr[d] : 0;
    }
    __syncthreads();
    int n = bcnt[b];
    const int* seg = pairs + (size_t)b * BCAP2;
#pragma unroll 4
    for (int i = threadIdx.x; i < n; i += 512) {
        int v = seg[i];
        int pos = atomicAdd(&lcur[v >> 17], 1);
        col[pos] = v & 0x1FFFF;
    }
    __syncthreads();
    for (int i = threadIdx.x; i < 256; i += 512) {
        int d = d0 + i;
        if (d < NN) {
            int rp = row_ptr[d];
            int end = lcur[i];                         // rp + deg
            int pend = rp + ((end - rp + 3) & ~3);
            for (int p = end; p < pend; ++p) col[p] = NN;  // sentinel: y[NN] == 0
        }
    }
}

// ---------------- W prep (merged): fp16 hi/lo split, MFMA B-fragment order ----------------

__global__ void wprep_kernel(const float* __restrict__ W_in, const float* __restrict__ WL,
                             _Float16* __restrict__ Bhi0, _Float16* __restrict__ Blo0,
                             _Float16* __restrict__ BhiL, _Float16* __restrict__ BloL) {
    int bid = blockIdx.x;
    if (bid < 32) {                              // init W: 8192 threads
        int t = bid * 256 + threadIdx.x;
        int lane = t & 63, nkk = t >> 6;
        int n = nkk >> 4, kk = nkk & 15;
        int scol = n * 16 + (lane & 15);
        int sr0 = kk * 32 + (lane >> 4) * 8;
#pragma unroll
        for (int j = 0; j < 8; ++j) {
            float w = W_in[(size_t)(sr0 + j) * HID + scol];
            _Float16 hi = (_Float16)w;
            _Float16 lo = (_Float16)(w - (float)hi);
            Bhi0[(size_t)t * 8 + j] = hi;
            Blo0[(size_t)t * 8 + j] = lo;
        }
    } else {                                     // layer Ws: 16384 threads
        int t = (bid - 32) * 256 + threadIdx.x;
        int layer = t >> 11;
        int r = t & 2047;
        int lane = r & 63, nkk = r >> 6;
        int n = nkk >> 2, kk = nkk & 3;
        const float* W = WL + (size_t)layer * HID * HID;
        int scol = n * 16 + (lane & 15);
        int sr0 = kk * 32 + (lane >> 4) * 8;
#pragma unroll
        for (int j = 0; j < 8; ++j) {
            float w = W[(size_t)(sr0 + j) * HID + scol];
            _Float16 hi = (_Float16)w;
            _Float16 lo = (_Float16)(w - (float)hi);
            BhiL[(size_t)t * 8 + j] = hi;
            BloL[(size_t)t * 8 + j] = lo;
        }
    }
}

// ---------------- init projection -> y = fp16(dinv*h0), x0 = fp16(0.1*h0) ----------------
// 32 rows/block, 512 thr, LDS 32KB -> 4 blocks/CU.

__device__ inline int xsw(int row, int blk) {      // fp16 offset in [rows][512] tile
    return row * 512 + ((blk ^ (row & 7)) << 3);
}

__global__ __launch_bounds__(512) void init_mfma_kernel(
    const float* __restrict__ x, const h16x8* __restrict__ Bhi, const h16x8* __restrict__ Blo,
    const float* __restrict__ b, const float* __restrict__ dinv,
    _Float16* __restrict__ ycur, _Float16* __restrict__ x0h) {
    __shared__ _Float16 xs[32 * 512];           // 32KB swizzled
    int t = threadIdx.x;
    int row0 = blockIdx.x * 32;                 // NN % 32 == 0: no tails anywhere

#pragma unroll
    for (int i = 0; i < 4; ++i) {               // linear 32B chunks: c = t + 512*i
        int c = t + 512 * i;
        int row = c >> 6, blk = c & 63;
        const float* p = x + (size_t)(row0 + row) * IN_DIM + blk * 8;
        float4 v0 = *(const float4*)p;
        float4 v1 = *(const float4*)(p + 4);
        h16x8 h;
        h[0] = (_Float16)v0.x; h[1] = (_Float16)v0.y;
        h[2] = (_Float16)v0.z; h[3] = (_Float16)v0.w;
        h[4] = (_Float16)v1.x; h[5] = (_Float16)v1.y;
        h[6] = (_Float16)v1.z; h[7] = (_Float16)v1.w;
        *(h16x8*)&xs[xsw(row, blk)] = h;
    }
    __syncthreads();

    int lane = t & 63, wid = t >> 6;            // wave = n-tile, m = 0..1
    int rsel = lane & 15, ksel = lane >> 4;

    f32x4 acc[2];
#pragma unroll
    for (int m = 0; m < 2; ++m) acc[m] = (f32x4){0.f, 0.f, 0.f, 0.f};

#pragma unroll
    for (int kk = 0; kk < 16; ++kk) {
        h16x8 bh = Bhi[(wid * 16 + kk) * 64 + lane];
        h16x8 bl = Blo[(wid * 16 + kk) * 64 + lane];
#pragma unroll
        for (int m = 0; m < 2; ++m) {
            h16x8 a = *(const h16x8*)&xs[xsw(m * 16 + rsel, kk * 4 + ksel)];
            acc[m] = __builtin_amdgcn_mfma_f32_16x16x32_f16(a, bh, acc[m], 0, 0, 0);
            acc[m] = __builtin_amdgcn_mfma_f32_16x16x32_f16(a, bl, acc[m], 0, 0, 0);
        }
    }

    int col = wid * 16 + rsel;
    float bias = b[col];
#pragma unroll
    for (int m = 0; m < 2; ++m) {
#pragma unroll
        for (int r = 0; r < 4; ++r) {
            int row = row0 + m * 16 + ksel * 4 + r;
            float v = acc[m][r] + bias;
            float di = dinv[row];
            ycur[(size_t)row * HID + col] = (_Float16)(di * v);
            x0h[(size_t)row * HID + col]  = (_Float16)(0.1f * v);
        }
    }
}

// ---------------- fused layer: agg(y) -> LDS -> MFMA -> relu/residual -> y_out ----------------
// LAST=1: fold final projection (sqrt(deg+1)*dinv == 1 -> out = sum v*w + b), skip yout.

__device__ inline int hsw(int row, int blk) {      // fp16 offset in [64][128] tile
    return row * 128 + ((blk ^ (row & 7)) << 3);
}

template <int LAST>
__global__ __launch_bounds__(512) void fused_layer_kernel(
    const _Float16* __restrict__ y, const _Float16* __restrict__ x0,
    const int* __restrict__ row_ptr, const int* __restrict__ col,
    const float* __restrict__ dinv,
    const h16x8* __restrict__ Bhi, const h16x8* __restrict__ Blo,
    float beta, _Float16* __restrict__ yout,
    const float* __restrict__ Wout, const float* __restrict__ bout,
    float* __restrict__ out) {
    __shared__ _Float16 hs[64 * 128];
    int t = threadIdx.x;
    int lane = t & 63, wid = t >> 6;
    int node0 = blockIdx.x * 64;
    int g = lane >> 4, q = lane & 15;

    // preload this wave's n-tile B fragments (independent of agg)
    h16x8 bh[4], bl[4];
#pragma unroll
    for (int kk = 0; kk < 4; ++kk) {
        bh[kk] = Bhi[(wid * 4 + kk) * 64 + lane];
        bl[kk] = Blo[(wid * 4 + kk) * 64 + lane];
    }

    const h16x8* x8 = (const h16x8*)y;
#pragma unroll
    for (int j = 0; j < 2; ++j) {
        int ln = wid * 8 + j * 4 + g;              // local row owned by this group
        int node = node0 + ln;
        int valid = node < NN;
        int nd = valid ? node : 0;
        float di = dinv[nd];
        h16x8 sv = x8[(size_t)nd * 16 + q];
        h16x8 zv = ((const h16x8*)x0)[(size_t)nd * 16 + q];   // pre-scaled 0.1*h0

        float acc[8];
#pragma unroll
        for (int jj = 0; jj < 8; ++jj) acc[jj] = 0.f;

        int p  = valid ? row_ptr[nd] : 0;
        int p1 = valid ? row_ptr[nd + 1] : 0;
#pragma unroll 2
        for (; p < p1; p += 4) {
            int4 c4 = *(const int4*)(col + p);     // uniform within group (broadcast)
            h16x8 v0 = x8[(size_t)c4.x * 16 + q];
            h16x8 v1 = x8[(size_t)c4.y * 16 + q];
            h16x8 v2 = x8[(size_t)c4.z * 16 + q];
            h16x8 v3 = x8[(size_t)c4.w * 16 + q];
#pragma unroll
            for (int jj = 0; jj < 8; ++jj)
                acc[jj] += ((float)v0[jj] + (float)v1[jj])
                         + ((float)v2[jj] + (float)v3[jj]);
        }

        float d9 = 0.9f * di;
        h16x8 o16;
#pragma unroll
        for (int jj = 0; jj < 8; ++jj) {
            float s = acc[jj] + (float)sv[jj];     // + self y_d
            o16[jj] = (_Float16)(d9 * s + (float)zv[jj]);
        }
        *(h16x8*)&hs[hsw(ln, q)] = o16;
    }
    __syncthreads();

    // ---- MFMA phase: wave = n-tile wid, 4 m-tiles ----
    int rsel = lane & 15, ksel = lane >> 4;
    f32x4 acc[4];
#pragma unroll
    for (int m = 0; m < 4; ++m) acc[m] = (f32x4){0.f, 0.f, 0.f, 0.f};

#pragma unroll
    for (int m = 0; m < 4; ++m)
#pragma unroll
        for (int kk = 0; kk < 4; ++kk) {
            h16x8 a = *(const h16x8*)&hs[hsw(m * 16 + rsel, kk * 4 + ksel)];
            acc[m] = __builtin_amdgcn_mfma_f32_16x16x32_f16(a, bh[kk], acc[m], 0, 0, 0);
            acc[m] = __builtin_amdgcn_mfma_f32_16x16x32_f16(a, bl[kk], acc[m], 0, 0, 0);
        }

    float ob = 1.0f - beta;
    int colw = wid * 16 + rsel;

    if constexpr (!LAST) {
#pragma unroll
        for (int m = 0; m < 4; ++m) {
#pragma unroll
            for (int r = 0; r < 4; ++r) {
                int lr = m * 16 + ksel * 4 + r;
                int row = node0 + lr;
                if (row < NN) {
                    float h = (float)hs[lr * 128 + (((colw >> 3) ^ (lr & 7)) << 3) + (colw & 7)];
                    float v = ob * h + beta * acc[m][r];
                    v = v > 0.f ? v : 0.f;
                    yout[(size_t)row * HID + colw] = (_Float16)(dinv[row] * v);
                }
            }
        }
    } else {
        __shared__ float red[64][9];               // [row][wave], padded
        float wv = Wout[colw];
#pragma unroll
        for (int m = 0; m < 4; ++m) {
#pragma unroll
            for (int r = 0; r < 4; ++r) {
                int lr = m * 16 + ksel * 4 + r;
                float h = (float)hs[lr * 128 + (((colw >> 3) ^ (lr & 7)) << 3) + (colw & 7)];
                float v = ob * h + beta * acc[m][r];
                v = v > 0.f ? v : 0.f;
                float pp = v * wv;                 // partial over this wave's 16 cols
                pp += __shfl_xor(pp, 1, 64);
                pp += __shfl_xor(pp, 2, 64);
                pp += __shfl_xor(pp, 4, 64);
                pp += __shfl_xor(pp, 8, 64);
                if (rsel == 0) red[lr][wid] = pp;
            }
        }
        __syncthreads();
        if (t < 64) {
            int row = node0 + t;
            if (row < NN) {
                float s = bout[0];
#pragma unroll
                for (int w = 0; w < 8; ++w) s += red[t][w];
                out[row] = s;
            }
        }
    }
}

// ---------------- host ----------------

extern "C" void kernel_launch(void* const* d_in, const int* in_sizes, int n_in,
                              void* d_out, int out_size, void* d_ws, size_t ws_size,
                              hipStream_t stream) {
    const float* x_in     = (const float*)d_in[0];
    const int*   ei       = (const int*)d_in[1];
    const float* W_in     = (const float*)d_in[3];
    const float* b_in     = (const float*)d_in[4];
    const float* W_layers = (const float*)d_in[5];
    const float* W_out    = (const float*)d_in[6];
    const float* b_out    = (const float*)d_in[7];
    float* out = (float*)d_out;

    const int* src = ei;
    const int* dst = ei + NE;

    char* ws = (char*)d_ws;
    size_t off = 0;
    auto alloc = [&](size_t bytes) {
        size_t p = off;
        off = (off + bytes + 255) & ~(size_t)255;
        return p;
    };
    int*   deg     = (int*)(ws + alloc((size_t)NN * 4));
    int*   bcnt    = (int*)(ws + alloc((size_t)NBUCK * 4));   // adjacent to deg: one memset
    float* dinv    = (float*)(ws + alloc((size_t)NN * 4));
    int*   row_ptr = (int*)(ws + alloc((size_t)(NN + 1) * 4));
    int*   bsum    = (int*)(ws + alloc((size_t)NB * 4));
    int*   col     = (int*)(ws + alloc((size_t)PADMAX * 4));
    size_t x0_off  = alloc((size_t)NN * HID * 2);
    _Float16* x0h  = (_Float16*)(ws + x0_off);
    int*   pairs   = (int*)(ws + x0_off);       // aliases x0h (7.2MB < 25.6MB):
                                                // CSR build completes before init_mfma
                                                // writes x0h (same stream)
    _Float16* bufA = (_Float16*)(ws + alloc((size_t)(NN + 16) * HID * 2));
    _Float16* bufB = (_Float16*)(ws + alloc((size_t)(NN + 16) * HID * 2));
    _Float16* Bhi0 = (_Float16*)(ws + alloc((size_t)IN_DIM * HID * 2));
    _Float16* Blo0 = (_Float16*)(ws + alloc((size_t)IN_DIM * HID * 2));
    _Float16* BhiL = (_Float16*)(ws + alloc((size_t)N_LAYERS * HID * HID * 2));
    _Float16* BloL = (_Float16*)(ws + alloc((size_t)N_LAYERS * HID * HID * 2));

    // one memset covers deg + (alignment gap) + bcnt
    hipMemsetAsync(deg, 0, (size_t)((char*)bcnt - (char*)deg) + (size_t)NBUCK * 4, stream);

    bucket2_kernel<<<(NE + EPB - 1) / EPB, 512, 0, stream>>>(src, dst, deg, bcnt, pairs);
    scan1_kernel<<<NB, 1024, 0, stream>>>(deg, bsum, bufA, bufB);
    scan3_kernel<<<NB, 1024, 0, stream>>>(deg, bsum, row_ptr, dinv);
    fill2_kernel<<<NBUCK, 512, 0, stream>>>(bcnt, pairs, row_ptr, col);

    wprep_kernel<<<96, 256, 0, stream>>>(W_in, W_layers, Bhi0, Blo0, BhiL, BloL);

    init_mfma_kernel<<<NN / 32, 512, 0, stream>>>(
        x_in, (const h16x8*)Bhi0, (const h16x8*)Blo0, b_in, dinv, bufA, x0h);

    _Float16* cur = bufA;
    _Float16* nxt = bufB;
    for (int l = 0; l < N_LAYERS - 1; ++l) {
        float beta = logf(0.5f / (float)(l + 1) + 1.0f);
        fused_layer_kernel<0><<<(NN + 63) / 64, 512, 0, stream>>>(
            cur, x0h, row_ptr, col, dinv,
            (const h16x8*)(BhiL + (size_t)l * HID * HID),
            (const h16x8*)(BloL + (size_t)l * HID * HID), beta, nxt,
            nullptr, nullptr, nullptr);
        _Float16* tmp = cur; cur = nxt; nxt = tmp;
    }
    {
        float beta = logf(0.5f / (float)N_LAYERS + 1.0f);
        fused_layer_kernel<1><<<(NN + 63) / 64, 512, 0, stream>>>(
            cur, x0h, row_ptr, col, dinv,
            (const h16x8*)(BhiL + (size_t)(N_LAYERS - 1) * HID * HID),
            (const h16x8*)(BloL + (size_t)(N_LAYERS - 1) * HID * HID), beta, nxt,
            W_out, b_out, out);
    }
}